// Round 7
// baseline (211.485 us; speedup 1.0000x reference)
//
#include <hip/hip_runtime.h>

#define Tn 1024
#define Hn 16
#define Dn 1024
#define DHn 64
#define KVSPLIT 2
// SCALE * log2(e): Q is pre-scaled by this, softmax then uses exp2 directly.
#define QSCALE 0.18033688011112042f

typedef unsigned short u16;
typedef unsigned long long ull;
typedef __bf16 bf16x8 __attribute__((ext_vector_type(8)));
typedef float f32x4 __attribute__((ext_vector_type(4)));

__device__ __forceinline__ u16 f2bf(float f) {
  union { float f; unsigned u; } v; v.f = f;
  return (u16)((v.u + 0x7FFFu + ((v.u >> 16) & 1u)) >> 16);
}
__device__ __forceinline__ float bf2f(u16 s) {
  union { unsigned u; float f; } v; v.u = ((unsigned)s) << 16;
  return v.f;
}
__device__ __forceinline__ f32x4 mfma16(bf16x8 a, bf16x8 b, f32x4 c) {
  return __builtin_amdgcn_mfma_f32_16x16x32_bf16(a, b, c, 0, 0, 0);
}

// ---------------- convert fp32 -> bf16 (linear) ----------------
__global__ void k_convert(const float* __restrict__ src, u16* __restrict__ dst, int n) {
  int i = (blockIdx.x * blockDim.x + threadIdx.x) * 4;
  if (i >= n) return;
  float4 v = *(const float4*)(src + i);
  union { u16 s[4]; uint2 u; } o;
  o.s[0] = f2bf(v.x); o.s[1] = f2bf(v.y); o.s[2] = f2bf(v.z); o.s[3] = f2bf(v.w);
  *(uint2*)(dst + i) = o.u;
}

// ---------------- pack bool mask bytes -> 64-bit words (bit k = mask[base+k]) ----------------
__global__ __launch_bounds__(256) void k_maskpack(const unsigned char* __restrict__ m,
                                                  unsigned long long* __restrict__ mb) {
  int wi = blockIdx.x * 4 + (threadIdx.x >> 6);
  int lane = threadIdx.x & 63;
  unsigned char v = m[((size_t)wi << 6) + lane];
  unsigned long long bal = __ballot(v != 0);
  if (lane == 0) mb[wi] = bal;
}

// ---------------- transpose + convert: W[K][N] fp32 -> Wt[N][K] bf16 ----------------
__global__ void k_transpose_convert(const float* __restrict__ W, u16* __restrict__ Wt) {
  __shared__ float tile[32][33];
  int n0 = blockIdx.x * 32, k0 = blockIdx.y * 32;
  int tx = threadIdx.x, ty = threadIdx.y; // (32,8)
  #pragma unroll
  for (int i = 0; i < 4; i++)
    tile[ty + 8*i][tx] = W[(size_t)(k0 + ty + 8*i) * Dn + n0 + tx];
  __syncthreads();
  #pragma unroll
  for (int i = 0; i < 4; i++)
    Wt[(size_t)(n0 + ty + 8*i) * Dn + k0 + tx] = f2bf(tile[tx][ty + 8*i]);
}

// ---------------- merged Q/KV projection GEMM, fp32 A with in-staging convert ----------------
// grid 768 x 256 threads. bx<256: Q (A=x, Bt=WqT, 8 n-blocks, scaled QSCALE);
// bx>=256: KV (A=context, Bt=WkT with WvT contiguous, 16 n-blocks).
// Block decode idx = n*32 + m -> blocks sharing the A-panel (same m, all n)
// have idx === m (mod 8) -> same XCD -> A-tile L2 reuse.
// Q/K write scattered [B,H,T,DH]; V written TRANSPOSED [B,H,DH,T].
__global__ __launch_bounds__(256) void k_proj(const float* __restrict__ x, const float* __restrict__ ctxI,
                                              const u16* __restrict__ WqT, const u16* __restrict__ WkvT,
                                              u16* __restrict__ Qb, u16* __restrict__ Kb, u16* __restrict__ Vb) {
  __shared__ __align__(16) u16 Al[128][40];
  __shared__ __align__(16) u16 Bl[128][40];
  int bx = blockIdx.x;
  bool isQ = bx < 256;
  int idx = isQ ? bx : bx - 256;
  int m0 = (idx & 31) * 128;
  int n0 = (idx >> 5) * 128;
  const float* A = isQ ? x : ctxI;
  const u16* Bt = isQ ? WqT : WkvT;
  u16* dst0 = isQ ? Qb : Kb;
  float scale = isQ ? QSCALE : 1.0f;
  int tid = threadIdx.x;
  int w = tid >> 6, lane = tid & 63, g = lane >> 4, lr = lane & 15;
  int wr = w >> 1, wc = w & 1;
  f32x4 acc[4][4] = {};
  int sr = tid >> 2, sc = tid & 3;
  const float* Ap0 = &A[(size_t)(m0 + sr) * Dn + sc * 8];
  const float* Ap1 = Ap0 + (size_t)64 * Dn;
  const u16* Bp0 = &Bt[(size_t)(n0 + sr) * Dn + sc * 8];
  const u16* Bp1 = Bp0 + (size_t)64 * Dn;
  float4 ra0a = *(const float4*)Ap0, ra0b = *(const float4*)(Ap0 + 4);
  float4 ra1a = *(const float4*)Ap1, ra1b = *(const float4*)(Ap1 + 4);
  int4 rb0 = *(const int4*)Bp0;
  int4 rb1 = *(const int4*)Bp1;
  for (int k0 = 0; k0 < Dn; k0 += 32) {
    __syncthreads();
    {
      union { u16 s[8]; int4 v; } c0, c1;
      c0.s[0]=f2bf(ra0a.x); c0.s[1]=f2bf(ra0a.y); c0.s[2]=f2bf(ra0a.z); c0.s[3]=f2bf(ra0a.w);
      c0.s[4]=f2bf(ra0b.x); c0.s[5]=f2bf(ra0b.y); c0.s[6]=f2bf(ra0b.z); c0.s[7]=f2bf(ra0b.w);
      c1.s[0]=f2bf(ra1a.x); c1.s[1]=f2bf(ra1a.y); c1.s[2]=f2bf(ra1a.z); c1.s[3]=f2bf(ra1a.w);
      c1.s[4]=f2bf(ra1b.x); c1.s[5]=f2bf(ra1b.y); c1.s[6]=f2bf(ra1b.z); c1.s[7]=f2bf(ra1b.w);
      *(int4*)&Al[sr][sc*8]      = c0.v;
      *(int4*)&Al[sr + 64][sc*8] = c1.v;
    }
    *(int4*)&Bl[sr][sc*8]      = rb0;
    *(int4*)&Bl[sr + 64][sc*8] = rb1;
    __syncthreads();
    if (k0 + 32 < Dn) {
      ra0a = *(const float4*)(Ap0 + k0 + 32); ra0b = *(const float4*)(Ap0 + k0 + 36);
      ra1a = *(const float4*)(Ap1 + k0 + 32); ra1b = *(const float4*)(Ap1 + k0 + 36);
      rb0 = *(const int4*)(Bp0 + k0 + 32);
      rb1 = *(const int4*)(Bp1 + k0 + 32);
    }
    bf16x8 a[4], b[4];
    #pragma unroll
    for (int mi = 0; mi < 4; mi++) a[mi] = *(const bf16x8*)&Al[wr*64 + mi*16 + lr][g*8];
    #pragma unroll
    for (int ni = 0; ni < 4; ni++) b[ni] = *(const bf16x8*)&Bl[wc*64 + ni*16 + lr][g*8];
    #pragma unroll
    for (int mi = 0; mi < 4; mi++)
      #pragma unroll
      for (int ni = 0; ni < 4; ni++)
        acc[mi][ni] = mfma16(a[mi], b[ni], acc[mi][ni]);
  }
  #pragma unroll
  for (int mi = 0; mi < 4; mi++)
    #pragma unroll
    for (int ni = 0; ni < 4; ni++) {
      int row0 = m0 + wr*64 + mi*16 + g*4;
      int col = n0 + wc*64 + ni*16 + lr;
      int bb = row0 >> 10, tt0 = row0 & 1023;
      int hh = col >> 6, dd = col & 63;
      if (hh < 16) {
        u16* p = dst0 + (((size_t)(bb*16 + hh) << 10) + (size_t)tt0) * 64 + dd;
        #pragma unroll
        for (int r = 0; r < 4; r++) p[(size_t)r * 64] = f2bf(acc[mi][ni][r] * scale);
      } else {
        union { u16 s[4]; uint2 u; } o;
        #pragma unroll
        for (int r = 0; r < 4; r++) o.s[r] = f2bf(acc[mi][ni][r]);
        *(uint2*)(Vb + (((size_t)((bb*16 + (hh - 16)) * 64 + dd)) << 10) + tt0) = o.u;
      }
    }
}

// ---------------- O-projection GEMM: bf16 A, linear write + fp32 bias ----------------
__global__ __launch_bounds__(256) void k_gemm_bt(const u16* __restrict__ A, const u16* __restrict__ Bt,
                                                 u16* __restrict__ dst0, const float* __restrict__ bias) {
  __shared__ __align__(16) u16 Al[128][40];
  __shared__ __align__(16) u16 Bl[128][40];
  int m0 = blockIdx.y * 128, n0 = blockIdx.x * 128;
  int tid = threadIdx.x;
  int w = tid >> 6, lane = tid & 63, g = lane >> 4, lr = lane & 15;
  int wr = w >> 1, wc = w & 1;
  f32x4 acc[4][4] = {};
  int sr = tid >> 2, sc = tid & 3;
  const u16* Ap0 = &A[(size_t)(m0 + sr) * Dn + sc * 8];
  const u16* Ap1 = &A[(size_t)(m0 + sr + 64) * Dn + sc * 8];
  const u16* Bp0 = &Bt[(size_t)(n0 + sr) * Dn + sc * 8];
  const u16* Bp1 = &Bt[(size_t)(n0 + sr + 64) * Dn + sc * 8];
  int4 ra0 = *(const int4*)Ap0;
  int4 ra1 = *(const int4*)Ap1;
  int4 rb0 = *(const int4*)Bp0;
  int4 rb1 = *(const int4*)Bp1;
  for (int k0 = 0; k0 < Dn; k0 += 32) {
    __syncthreads();
    *(int4*)&Al[sr][sc*8]      = ra0;
    *(int4*)&Al[sr + 64][sc*8] = ra1;
    *(int4*)&Bl[sr][sc*8]      = rb0;
    *(int4*)&Bl[sr + 64][sc*8] = rb1;
    __syncthreads();
    if (k0 + 32 < Dn) {
      ra0 = *(const int4*)(Ap0 + k0 + 32);
      ra1 = *(const int4*)(Ap1 + k0 + 32);
      rb0 = *(const int4*)(Bp0 + k0 + 32);
      rb1 = *(const int4*)(Bp1 + k0 + 32);
    }
    bf16x8 a[4], b[4];
    #pragma unroll
    for (int mi = 0; mi < 4; mi++) a[mi] = *(const bf16x8*)&Al[wr*64 + mi*16 + lr][g*8];
    #pragma unroll
    for (int ni = 0; ni < 4; ni++) b[ni] = *(const bf16x8*)&Bl[wc*64 + ni*16 + lr][g*8];
    #pragma unroll
    for (int mi = 0; mi < 4; mi++)
      #pragma unroll
      for (int ni = 0; ni < 4; ni++)
        acc[mi][ni] = mfma16(a[mi], b[ni], acc[mi][ni]);
  }
  #pragma unroll
  for (int mi = 0; mi < 4; mi++)
    #pragma unroll
    for (int ni = 0; ni < 4; ni++) {
      int row0 = m0 + wr*64 + mi*16 + g*4;
      int col = n0 + wc*64 + ni*16 + lr;
      #pragma unroll
      for (int r = 0; r < 4; r++)
        dst0[(size_t)(row0 + r) * Dn + col] = f2bf(acc[mi][ni][r] + bias[col]);
    }
}

// ---------------- flash attention with Music-Transformer skew ----------------
// grid (KVSPLIT*B, H, T/128), block 512 = 8 waves sharing one K/V staging.
// 128 kv per barrier-iter. ALL barrier-independent work (mask loads, E loads,
// REL MFMAs, skew bpermutes) is hoisted ABOVE the first barrier: it executes
// while other waves finish PV, converting barrier-wait into useful work and
// shortening the post-barrier critical path to ds_read->S->exp2->RP->PV.
// Fixed-max softmax (scores bounded), row-sum via ones-MFMA, REL band carry.
__global__ __launch_bounds__(512, 2) void k_attn(const u16* __restrict__ Qb, const u16* __restrict__ Kb,
                                              const u16* __restrict__ VT, const u16* __restrict__ Eb,
                                              const unsigned long long* __restrict__ mbits,
                                              u16* __restrict__ Opart, float* __restrict__ Lpart) {
  __shared__ __align__(16) u16 KlF[128 * 64];   // XOR-swizzled: u16 idx = row*64 + (col ^ ((row&7)<<3))
  __shared__ __align__(16) u16 Vt[64][136];     // V^T tile: Vt[d][kv-local 0..127]
  __shared__ __align__(16) u16 RP[8][16][72];   // per-wave P tile (bf16), reused across sub-tiles
  int h = blockIdx.y;
  int zi = blockIdx.x;            // s*B + b
  int b = zi & 3;
  int kv0 = (zi >> 2) * (Tn / KVSPLIT);
  int kv_end = kv0 + Tn / KVSPLIT;
  int q0 = blockIdx.z * 128;
  int tid = threadIdx.x;
  int w = tid >> 6, lane = tid & 63, g = lane >> 4, lr = lane & 15;
  int qw0 = q0 + w * 16;
  size_t headoff = (size_t)(b * Hn + h) * Tn * DHn;
  bf16x8 qf0 = *(const bf16x8*)&Qb[headoff + (size_t)(qw0 + lr)*64 + g*8];
  bf16x8 qf1 = *(const bf16x8*)&Qb[headoff + (size_t)(qw0 + lr)*64 + 32 + g*8];
  f32x4 O[4] = {};
  f32x4 Os = {0.f, 0.f, 0.f, 0.f};
  union { u16 s[8]; bf16x8 v; } one8;
  #pragma unroll
  for (int j = 0; j < 8; j++) one8.s[j] = 0x3F80u; // bf16 1.0

  // loop-invariant skew-shuffle source lanes + register-set predicates:
  // skew(rowq,col) = REL[rowq][col-rowq+15]; producer lane = same g-group,
  // lane (lr-rowq+15)&15, register-set c (if lr<=rowq) else c+1, same reg r.
  int srcl[4]; bool psel[4];
  #pragma unroll
  for (int r = 0; r < 4; r++) {
    int rowq = g*4 + r;
    srcl[r] = (lane & 48) + ((lr - rowq + 15) & 15);
    psel[r] = (lr <= rowq);
  }
  const unsigned long long* mrow = mbits + ((size_t)(b * Tn + qw0 + g*4) << 4);

  // REL carry prologue: jt=0 window of the first tile
  f32x4 carry = {0.f, 0.f, 0.f, 0.f};
  {
    int rmin0 = kv0 - qw0 + 1008;
    const u16* ep = &Eb[(size_t)(rmin0 + lr) * 64 + g*8];
    carry = mfma16(qf0, *(const bf16x8*)ep, carry);
    carry = mfma16(qf1, *(const bf16x8*)(ep + 32), carry);
  }

  // staging (512 threads, 128-kv iter):
  //   K: 128 rows x 64 cols -> rows tid>>3 and +64, chunk (tid&7)*8 (XOR-swizzled)
  //   V^T: 64 rows x 128 cols -> rows tid>>4 and +32, chunk (tid&15)*8
  int sKr = tid >> 3, sKc = (tid & 7) * 8;
  int kswz = sKc ^ ((sKr & 7) << 3);       // (sKr+64)&7 == sKr&7 -> same swizzle both rows
  int sVr = tid >> 4, sVc = (tid & 15) * 8;
  const u16* Kgs = Kb + headoff + (size_t)sKr * 64 + sKc;
  const u16* Vgs = VT + headoff + (size_t)sVr * 1024 + sVc;
  int4 kA = *(const int4*)(Kgs + (size_t)kv0 * 64);
  int4 kB = *(const int4*)(Kgs + (size_t)(kv0 + 64) * 64);
  int4 vA = *(const int4*)(Vgs + kv0);
  int4 vB = *(const int4*)(Vgs + 32 * 1024 + kv0);

  int kread = (g * 8) ^ ((lr & 7) << 3);      // swizzled col for K fragment, low half
  int kread2 = (32 + g * 8) ^ ((lr & 7) << 3);

  for (int k0 = kv0; k0 < kv_end; k0 += 128) {
    // ======== pre-barrier: independent of LDS staging ========
    uint2 mw[2][4];
    #pragma unroll
    for (int t = 0; t < 2; t++)
      #pragma unroll
      for (int r = 0; r < 4; r++)
        mw[t][r] = *(const uint2*)(mrow + (size_t)r * 16 + (k0 >> 6) + t);

    int rmin0 = k0 - qw0 + 1008;
    f32x4 Rm0[5];
    Rm0[0] = carry;
    __builtin_amdgcn_s_setprio(1);
    #pragma unroll
    for (int jt = 1; jt < 5; jt++) {
      const u16* ep = &Eb[(size_t)(rmin0 + jt*16 + lr) * 64 + g*8];
      f32x4 R = {0.f, 0.f, 0.f, 0.f};
      R = mfma16(qf0, *(const bf16x8*)ep, R);
      R = mfma16(qf1, *(const bf16x8*)(ep + 32), R);
      Rm0[jt] = R;
    }
    f32x4 Rm1[5];
    Rm1[0] = Rm0[4];
    #pragma unroll
    for (int jt = 1; jt < 5; jt++) {
      const u16* ep = &Eb[(size_t)(rmin0 + 64 + jt*16 + lr) * 64 + g*8];
      f32x4 R = {0.f, 0.f, 0.f, 0.f};
      R = mfma16(qf0, *(const bf16x8*)ep, R);
      R = mfma16(qf1, *(const bf16x8*)(ep + 32), R);
      Rm1[jt] = R;
    }
    __builtin_amdgcn_s_setprio(0);
    carry = Rm1[4];
    float sh0[5][4], sh1[5][4];
    #pragma unroll
    for (int s5 = 0; s5 < 5; s5++)
      #pragma unroll
      for (int r = 0; r < 4; r++) {
        sh0[s5][r] = __shfl(Rm0[s5][r], srcl[r], 64);
        sh1[s5][r] = __shfl(Rm1[s5][r], srcl[r], 64);
      }

    // ======== staging ========
    __syncthreads();
    *(int4*)&KlF[sKr * 64 + kswz]        = kA;
    *(int4*)&KlF[(sKr + 64) * 64 + kswz] = kB;
    *(int4*)&Vt[sVr][sVc]                = vA;
    *(int4*)&Vt[sVr + 32][sVc]           = vB;
    __syncthreads();
    if (k0 + 128 < kv_end) {   // earliest issue -> max lead over next-iter consumption
      kA = *(const int4*)(Kgs + (size_t)(k0 + 128) * 64);
      kB = *(const int4*)(Kgs + (size_t)(k0 + 192) * 64);
      vA = *(const int4*)(Vgs + k0 + 128);
      vB = *(const int4*)(Vgs + 32 * 1024 + k0 + 128);
    }

    // ======== compute ========
    bf16x8 pa00, pa01, pa10, pa11;
    f32x4 S0[4];
    __builtin_amdgcn_s_setprio(1);
    #pragma unroll
    for (int c = 0; c < 4; c++) {
      int krow = c*16 + lr;
      f32x4 z = {0.f, 0.f, 0.f, 0.f};
      z = mfma16(qf0, *(const bf16x8*)&KlF[krow*64 + kread], z);
      z = mfma16(qf1, *(const bf16x8*)&KlF[krow*64 + kread2], z);
      S0[c] = z;
    }
    __builtin_amdgcn_s_setprio(0);
    #pragma unroll
    for (int c = 0; c < 4; c++)
      #pragma unroll
      for (int r = 0; r < 4; r++) {
        float s = S0[c][r] + (psel[r] ? sh0[c][r] : sh0[c+1][r]);
        unsigned bit;
        if (c == 0)      bit = (mw[0][r].x >> lr) & 1u;
        else if (c == 1) bit = (mw[0][r].x >> (16 + lr)) & 1u;
        else if (c == 2) bit = (mw[0][r].y >> lr) & 1u;
        else             bit = (mw[0][r].y >> (16 + lr)) & 1u;
        s = bit ? -1e9f : s;
        RP[w][g*4 + r][c*16 + lr] = f2bf(__builtin_amdgcn_exp2f(s));
      }
    pa00 = *(const bf16x8*)&RP[w][lr][g*8];
    pa01 = *(const bf16x8*)&RP[w][lr][32 + g*8];

    f32x4 S1[4];
    __builtin_amdgcn_s_setprio(1);
    #pragma unroll
    for (int c = 0; c < 4; c++) {
      int krow = 64 + c*16 + lr;
      f32x4 z = {0.f, 0.f, 0.f, 0.f};
      z = mfma16(qf0, *(const bf16x8*)&KlF[krow*64 + kread], z);
      z = mfma16(qf1, *(const bf16x8*)&KlF[krow*64 + kread2], z);
      S1[c] = z;
    }
    __builtin_amdgcn_s_setprio(0);
    #pragma unroll
    for (int c = 0; c < 4; c++)
      #pragma unroll
      for (int r = 0; r < 4; r++) {
        float s = S1[c][r] + (psel[r] ? sh1[c][r] : sh1[c+1][r]);
        unsigned bit;
        if (c == 0)      bit = (mw[1][r].x >> lr) & 1u;
        else if (c == 1) bit = (mw[1][r].x >> (16 + lr)) & 1u;
        else if (c == 2) bit = (mw[1][r].y >> lr) & 1u;
        else             bit = (mw[1][r].y >> (16 + lr)) & 1u;
        s = bit ? -1e9f : s;
        RP[w][g*4 + r][c*16 + lr] = f2bf(__builtin_amdgcn_exp2f(s));
      }
    pa10 = *(const bf16x8*)&RP[w][lr][g*8];
    pa11 = *(const bf16x8*)&RP[w][lr][32 + g*8];

    // ======== PV + row-sum (LDS + MFMA only) ========
    __builtin_amdgcn_s_setprio(1);
    #pragma unroll
    for (int ct = 0; ct < 4; ct++) {
      bf16x8 vf0 = *(const bf16x8*)&Vt[ct*16 + lr][g*8];
      bf16x8 vf1 = *(const bf16x8*)&Vt[ct*16 + lr][32 + g*8];
      O[ct] = mfma16(pa00, vf0, O[ct]);
      O[ct] = mfma16(pa01, vf1, O[ct]);
      bf16x8 vf2 = *(const bf16x8*)&Vt[ct*16 + lr][64 + g*8];
      bf16x8 vf3 = *(const bf16x8*)&Vt[ct*16 + lr][96 + g*8];
      O[ct] = mfma16(pa10, vf2, O[ct]);
      O[ct] = mfma16(pa11, vf3, O[ct]);
    }
    Os = mfma16(pa00, one8.v, Os);
    Os = mfma16(pa01, one8.v, Os);
    Os = mfma16(pa10, one8.v, Os);
    Os = mfma16(pa11, one8.v, Os);
    __builtin_amdgcn_s_setprio(0);
  }
  // store unnormalized partial O (bf16) and row-sums l (f32)
  #pragma unroll
  for (int ct = 0; ct < 4; ct++)
    #pragma unroll
    for (int r = 0; r < 4; r++) {
      int rowq = g*4 + r, col = ct*16 + lr;
      Opart[((size_t)zi * Tn + qw0 + rowq) * 1024 + h*64 + col] = f2bf(O[ct][r]);
    }
  if (lr == 0) {
    #pragma unroll
    for (int r = 0; r < 4; r++)
      Lpart[((size_t)zi * Hn + h) * Tn + qw0 + g*4 + r] = Os[r];
  }
}

// ---------------- combine KV-split partials: ctx = (sum O_s) / (sum l_s) ----------------
__global__ __launch_bounds__(256) void k_combine(const u16* __restrict__ Op, const float* __restrict__ Lp,
                                                 u16* __restrict__ ctx) {
  int m = blockIdx.x;            // b*T + t
  int b = m >> 10, t = m & 1023;
  int tid = threadIdx.x;
  int j0 = tid * 4, h = j0 >> 6;
  float l = Lp[((size_t)b * Hn + h) * Tn + t] +
            Lp[((size_t)(4 + b) * Hn + h) * Tn + t];
  float invl = 1.f / l;
  union { uint2 u; u16 s[4]; } a, c;
  a.u = *(const uint2*)&Op[((size_t)b * Tn + t) * 1024 + j0];
  c.u = *(const uint2*)&Op[((size_t)(4 + b) * Tn + t) * 1024 + j0];
  union { u16 s[4]; uint2 u; } o;
  #pragma unroll
  for (int i = 0; i < 4; i++)
    o.s[i] = f2bf((bf2f(a.s[i]) + bf2f(c.s[i])) * invl);
  *(uint2*)&ctx[((size_t)b * Tn + t) * 1024 + j0] = o.u;
}

// ---------------- residual + LayerNorm ----------------
__global__ __launch_bounds__(256) void k_ln(const float* __restrict__ x, const u16* __restrict__ o,
                                            const float* __restrict__ gamma, const float* __restrict__ beta,
                                            float* __restrict__ out) {
  int m = blockIdx.x, tid = threadIdx.x;
  int w = tid >> 6, lane = tid & 63;
  const float* xr = x + (size_t)m * Dn;
  const u16* orow = o + (size_t)m * Dn;
  float4 xv = *(const float4*)&xr[tid*4];
  union { uint2 u; u16 s[4]; } ou;
  ou.u = *(const uint2*)&orow[tid*4];
  float y[4];
  y[0] = xv.x + bf2f(ou.s[0]);
  y[1] = xv.y + bf2f(ou.s[1]);
  y[2] = xv.z + bf2f(ou.s[2]);
  y[3] = xv.w + bf2f(ou.s[3]);
  float s = y[0]+y[1]+y[2]+y[3];
  float s2 = y[0]*y[0]+y[1]*y[1]+y[2]*y[2]+y[3]*y[3];
  #pragma unroll
  for (int off = 1; off < 64; off <<= 1) { s += __shfl_xor(s, off); s2 += __shfl_xor(s2, off); }
  __shared__ float red[8];
  if (lane == 0) { red[w] = s; red[4 + w] = s2; }
  __syncthreads();
  float Sa = red[0]+red[1]+red[2]+red[3];
  float Sb = red[4]+red[5]+red[6]+red[7];
  float mu = Sa * (1.f/1024.f);
  float var = Sb * (1.f/1024.f) - mu*mu;
  float rstd = rsqrtf(var + 1e-5f);
  #pragma unroll
  for (int i = 0; i < 4; i++) {
    int j = tid*4 + i;
    out[(size_t)m*Dn + j] = (y[i] - mu) * rstd * gamma[j] + beta[j];
  }
}

extern "C" void kernel_launch(void* const* d_in, const int* in_sizes, int n_in,
                              void* d_out, int out_size, void* d_ws, size_t ws_size,
                              hipStream_t stream) {
  const float* x    = (const float*)d_in[0];
  const float* ctxI = (const float*)d_in[1];
  const unsigned char* mask = (const unsigned char*)d_in[2];
  const float* lut  = (const float*)d_in[3];
  const float* Wq   = (const float*)d_in[4];
  const float* Wk   = (const float*)d_in[5];
  const float* Wv   = (const float*)d_in[6];
  const float* Wo   = (const float*)d_in[7];
  const float* bo   = (const float*)d_in[8];
  const float* gamma= (const float*)d_in[9];
  const float* beta = (const float*)d_in[10];
  float* out = (float*)d_out;

  u16* ws0  = (u16*)d_ws;              // 16.8 MB scratch: Opart during attn
  u16* WqT  = ws0 + 8388608;
  u16* WkT  = WqT + 1048576;
  u16* WvT  = WkT + 1048576;   // contiguous with WkT -> fused KV GEMM reads [2048][1024]
  u16* WoT  = WvT + 1048576;
  u16* Ebf  = WoT + 1048576;
  u16* Qbf  = Ebf + 131072;
  u16* Kbf  = Qbf + 4194304;
  u16* Vbf  = Kbf + 4194304;   // holds V^T [B,H,DH,T]
  u16* ctxb = Vbf + 4194304;
  u16* obf  = ctxb + 4194304;
  unsigned long long* mbits = (unsigned long long*)(obf + 4194304); // 65536 words = 512 KB

  // KV-split partial buffers alias regions dead during attn:
  //   Opart (16.8 MB, bf16, [2*B][T][H*DH]) in ws0 (pure scratch now).
  //   Lpart (512 KB, f32, [2*B][H][T]) over obf (first written by the O-GEMM, later).
  u16* Opart = ws0;
  float* Lpart = (float*)obf;

  k_maskpack<<<16384, 256, 0, stream>>>(mask, mbits);
  k_convert<<<128, 256, 0, stream>>>(lut, Ebf, 131008);
  dim3 tb(32, 8), tg(32, 32);
  k_transpose_convert<<<tg, tb, 0, stream>>>(Wq, WqT);
  k_transpose_convert<<<tg, tb, 0, stream>>>(Wk, WkT);
  k_transpose_convert<<<tg, tb, 0, stream>>>(Wv, WvT);
  k_transpose_convert<<<tg, tb, 0, stream>>>(Wo, WoT);
  k_proj<<<768, 256, 0, stream>>>(x, ctxI, WqT, WkT, Qbf, Kbf, Vbf);
  k_attn<<<dim3(8, 16, 8), 512, 0, stream>>>(Qbf, Kbf, Vbf, Ebf, mbits, Opart, Lpart);
  k_combine<<<4096, 256, 0, stream>>>(Opart, Lpart, ctxb);
  k_gemm_bt<<<dim3(8, 32), 256, 0, stream>>>(ctxb, WoT, obf, bo);
  k_ln<<<4096, 256, 0, stream>>>(x, obf, gamma, beta, out);
}

// Round 8
// 189.506 us; speedup vs baseline: 1.1160x; 1.1160x over previous
//
#include <hip/hip_runtime.h>

#define Tn 1024
#define Hn 16
#define Dn 1024
#define DHn 64
// SCALE * log2(e): Q is pre-scaled by this, softmax then uses exp2 directly.
#define QSCALE 0.18033688011112042f

typedef unsigned short u16;
typedef unsigned long long ull;
typedef __bf16 bf16x8 __attribute__((ext_vector_type(8)));
typedef float f32x4 __attribute__((ext_vector_type(4)));

__device__ __forceinline__ u16 f2bf(float f) {
  union { float f; unsigned u; } v; v.f = f;
  return (u16)((v.u + 0x7FFFu + ((v.u >> 16) & 1u)) >> 16);
}
__device__ __forceinline__ float bf2f(u16 s) {
  union { unsigned u; float f; } v; v.u = ((unsigned)s) << 16;
  return v.f;
}
__device__ __forceinline__ f32x4 mfma16(bf16x8 a, bf16x8 b, f32x4 c) {
  return __builtin_amdgcn_mfma_f32_16x16x32_bf16(a, b, c, 0, 0, 0);
}

// ---------------- convert fp32 -> bf16 (linear) ----------------
__global__ void k_convert(const float* __restrict__ src, u16* __restrict__ dst, int n) {
  int i = (blockIdx.x * blockDim.x + threadIdx.x) * 4;
  if (i >= n) return;
  float4 v = *(const float4*)(src + i);
  union { u16 s[4]; uint2 u; } o;
  o.s[0] = f2bf(v.x); o.s[1] = f2bf(v.y); o.s[2] = f2bf(v.z); o.s[3] = f2bf(v.w);
  *(uint2*)(dst + i) = o.u;
}

// ---------------- pack bool mask bytes -> 64-bit words (bit k = mask[base+k]) ----------------
__global__ __launch_bounds__(256) void k_maskpack(const unsigned char* __restrict__ m,
                                                  unsigned long long* __restrict__ mb) {
  int wi = blockIdx.x * 4 + (threadIdx.x >> 6);
  int lane = threadIdx.x & 63;
  unsigned char v = m[((size_t)wi << 6) + lane];
  unsigned long long bal = __ballot(v != 0);
  if (lane == 0) mb[wi] = bal;
}

// ---------------- transpose + convert: W[K][N] fp32 -> Wt[N][K] bf16 ----------------
__global__ void k_transpose_convert(const float* __restrict__ W, u16* __restrict__ Wt) {
  __shared__ float tile[32][33];
  int n0 = blockIdx.x * 32, k0 = blockIdx.y * 32;
  int tx = threadIdx.x, ty = threadIdx.y; // (32,8)
  #pragma unroll
  for (int i = 0; i < 4; i++)
    tile[ty + 8*i][tx] = W[(size_t)(k0 + ty + 8*i) * Dn + n0 + tx];
  __syncthreads();
  #pragma unroll
  for (int i = 0; i < 4; i++)
    Wt[(size_t)(n0 + ty + 8*i) * Dn + k0 + tx] = f2bf(tile[tx][ty + 8*i]);
}

// ---------------- merged Q/KV projection GEMM, fp32 A with in-staging convert ----------------
// grid 768 x 256 threads. bx<256: Q (A=x, Bt=WqT, 8 n-blocks, scaled QSCALE);
// bx>=256: KV (A=context, Bt=WkT with WvT contiguous, 16 n-blocks).
// Block decode idx = n*32 + m -> blocks sharing the A-panel (same m, all n)
// have idx === m (mod 8) -> same XCD -> A-tile L2 reuse.
// Q/K write scattered [B,H,T,DH]; V written TRANSPOSED [B,H,DH,T].
__global__ __launch_bounds__(256) void k_proj(const float* __restrict__ x, const float* __restrict__ ctxI,
                                              const u16* __restrict__ WqT, const u16* __restrict__ WkvT,
                                              u16* __restrict__ Qb, u16* __restrict__ Kb, u16* __restrict__ Vb) {
  __shared__ __align__(16) u16 Al[128][40];
  __shared__ __align__(16) u16 Bl[128][40];
  int bx = blockIdx.x;
  bool isQ = bx < 256;
  int idx = isQ ? bx : bx - 256;
  int m0 = (idx & 31) * 128;
  int n0 = (idx >> 5) * 128;
  const float* A = isQ ? x : ctxI;
  const u16* Bt = isQ ? WqT : WkvT;
  u16* dst0 = isQ ? Qb : Kb;
  float scale = isQ ? QSCALE : 1.0f;
  int tid = threadIdx.x;
  int w = tid >> 6, lane = tid & 63, g = lane >> 4, lr = lane & 15;
  int wr = w >> 1, wc = w & 1;
  f32x4 acc[4][4] = {};
  int sr = tid >> 2, sc = tid & 3;
  const float* Ap0 = &A[(size_t)(m0 + sr) * Dn + sc * 8];
  const float* Ap1 = Ap0 + (size_t)64 * Dn;
  const u16* Bp0 = &Bt[(size_t)(n0 + sr) * Dn + sc * 8];
  const u16* Bp1 = Bp0 + (size_t)64 * Dn;
  float4 ra0a = *(const float4*)Ap0, ra0b = *(const float4*)(Ap0 + 4);
  float4 ra1a = *(const float4*)Ap1, ra1b = *(const float4*)(Ap1 + 4);
  int4 rb0 = *(const int4*)Bp0;
  int4 rb1 = *(const int4*)Bp1;
  for (int k0 = 0; k0 < Dn; k0 += 32) {
    __syncthreads();
    {
      union { u16 s[8]; int4 v; } c0, c1;
      c0.s[0]=f2bf(ra0a.x); c0.s[1]=f2bf(ra0a.y); c0.s[2]=f2bf(ra0a.z); c0.s[3]=f2bf(ra0a.w);
      c0.s[4]=f2bf(ra0b.x); c0.s[5]=f2bf(ra0b.y); c0.s[6]=f2bf(ra0b.z); c0.s[7]=f2bf(ra0b.w);
      c1.s[0]=f2bf(ra1a.x); c1.s[1]=f2bf(ra1a.y); c1.s[2]=f2bf(ra1a.z); c1.s[3]=f2bf(ra1a.w);
      c1.s[4]=f2bf(ra1b.x); c1.s[5]=f2bf(ra1b.y); c1.s[6]=f2bf(ra1b.z); c1.s[7]=f2bf(ra1b.w);
      *(int4*)&Al[sr][sc*8]      = c0.v;
      *(int4*)&Al[sr + 64][sc*8] = c1.v;
    }
    *(int4*)&Bl[sr][sc*8]      = rb0;
    *(int4*)&Bl[sr + 64][sc*8] = rb1;
    __syncthreads();
    if (k0 + 32 < Dn) {
      ra0a = *(const float4*)(Ap0 + k0 + 32); ra0b = *(const float4*)(Ap0 + k0 + 36);
      ra1a = *(const float4*)(Ap1 + k0 + 32); ra1b = *(const float4*)(Ap1 + k0 + 36);
      rb0 = *(const int4*)(Bp0 + k0 + 32);
      rb1 = *(const int4*)(Bp1 + k0 + 32);
    }
    bf16x8 a[4], b[4];
    #pragma unroll
    for (int mi = 0; mi < 4; mi++) a[mi] = *(const bf16x8*)&Al[wr*64 + mi*16 + lr][g*8];
    #pragma unroll
    for (int ni = 0; ni < 4; ni++) b[ni] = *(const bf16x8*)&Bl[wc*64 + ni*16 + lr][g*8];
    #pragma unroll
    for (int mi = 0; mi < 4; mi++)
      #pragma unroll
      for (int ni = 0; ni < 4; ni++)
        acc[mi][ni] = mfma16(a[mi], b[ni], acc[mi][ni]);
  }
  #pragma unroll
  for (int mi = 0; mi < 4; mi++)
    #pragma unroll
    for (int ni = 0; ni < 4; ni++) {
      int row0 = m0 + wr*64 + mi*16 + g*4;
      int col = n0 + wc*64 + ni*16 + lr;
      int bb = row0 >> 10, tt0 = row0 & 1023;
      int hh = col >> 6, dd = col & 63;
      if (hh < 16) {
        u16* p = dst0 + (((size_t)(bb*16 + hh) << 10) + (size_t)tt0) * 64 + dd;
        #pragma unroll
        for (int r = 0; r < 4; r++) p[(size_t)r * 64] = f2bf(acc[mi][ni][r] * scale);
      } else {
        union { u16 s[4]; uint2 u; } o;
        #pragma unroll
        for (int r = 0; r < 4; r++) o.s[r] = f2bf(acc[mi][ni][r]);
        *(uint2*)(Vb + (((size_t)((bb*16 + (hh - 16)) * 64 + dd)) << 10) + tt0) = o.u;
      }
    }
}

// ---------------- O-projection GEMM: bf16 A, linear write + fp32 bias ----------------
__global__ __launch_bounds__(256) void k_gemm_bt(const u16* __restrict__ A, const u16* __restrict__ Bt,
                                                 u16* __restrict__ dst0, const float* __restrict__ bias) {
  __shared__ __align__(16) u16 Al[128][40];
  __shared__ __align__(16) u16 Bl[128][40];
  int m0 = blockIdx.y * 128, n0 = blockIdx.x * 128;
  int tid = threadIdx.x;
  int w = tid >> 6, lane = tid & 63, g = lane >> 4, lr = lane & 15;
  int wr = w >> 1, wc = w & 1;
  f32x4 acc[4][4] = {};
  int sr = tid >> 2, sc = tid & 3;
  const u16* Ap0 = &A[(size_t)(m0 + sr) * Dn + sc * 8];
  const u16* Ap1 = &A[(size_t)(m0 + sr + 64) * Dn + sc * 8];
  const u16* Bp0 = &Bt[(size_t)(n0 + sr) * Dn + sc * 8];
  const u16* Bp1 = &Bt[(size_t)(n0 + sr + 64) * Dn + sc * 8];
  int4 ra0 = *(const int4*)Ap0;
  int4 ra1 = *(const int4*)Ap1;
  int4 rb0 = *(const int4*)Bp0;
  int4 rb1 = *(const int4*)Bp1;
  for (int k0 = 0; k0 < Dn; k0 += 32) {
    __syncthreads();
    *(int4*)&Al[sr][sc*8]      = ra0;
    *(int4*)&Al[sr + 64][sc*8] = ra1;
    *(int4*)&Bl[sr][sc*8]      = rb0;
    *(int4*)&Bl[sr + 64][sc*8] = rb1;
    __syncthreads();
    if (k0 + 32 < Dn) {
      ra0 = *(const int4*)(Ap0 + k0 + 32);
      ra1 = *(const int4*)(Ap1 + k0 + 32);
      rb0 = *(const int4*)(Bp0 + k0 + 32);
      rb1 = *(const int4*)(Bp1 + k0 + 32);
    }
    bf16x8 a[4], b[4];
    #pragma unroll
    for (int mi = 0; mi < 4; mi++) a[mi] = *(const bf16x8*)&Al[wr*64 + mi*16 + lr][g*8];
    #pragma unroll
    for (int ni = 0; ni < 4; ni++) b[ni] = *(const bf16x8*)&Bl[wc*64 + ni*16 + lr][g*8];
    #pragma unroll
    for (int mi = 0; mi < 4; mi++)
      #pragma unroll
      for (int ni = 0; ni < 4; ni++)
        acc[mi][ni] = mfma16(a[mi], b[ni], acc[mi][ni]);
  }
  #pragma unroll
  for (int mi = 0; mi < 4; mi++)
    #pragma unroll
    for (int ni = 0; ni < 4; ni++) {
      int row0 = m0 + wr*64 + mi*16 + g*4;
      int col = n0 + wc*64 + ni*16 + lr;
      #pragma unroll
      for (int r = 0; r < 4; r++)
        dst0[(size_t)(row0 + r) * Dn + col] = f2bf(acc[mi][ni][r] + bias[col]);
    }
}

// ---------------- flash attention with Music-Transformer skew ----------------
// grid (B, H, T/128), block 512 = 8 waves sharing one K/V staging.
// 128 kv per barrier-iter (two 16x64 sub-tiles per wave). Load-issue order is
// arranged for in-order vmcnt retirement: mask+E loads (L2-hot) are issued
// BEFORE the HBM K/V prefetch, so E consumption never queues behind HBM.
// Fixed-max softmax (scores bounded), row-sum via ones-MFMA. REL band carry:
// tile t+1's jt=0 window == tile t's jt=4 -> carried in registers.
// Full kv range per block (no split); normalized ctx written directly.
__global__ __launch_bounds__(512, 2) void k_attn(const u16* __restrict__ Qb, const u16* __restrict__ Kb,
                                              const u16* __restrict__ VT, const u16* __restrict__ Eb,
                                              const unsigned long long* __restrict__ mbits,
                                              u16* __restrict__ ctx) {
  __shared__ __align__(16) u16 KlF[128 * 64];   // XOR-swizzled: u16 idx = row*64 + (col ^ ((row&7)<<3))
  __shared__ __align__(16) u16 Vt[64][136];     // V^T tile: Vt[d][kv-local 0..127]
  __shared__ __align__(16) u16 RP[8][16][72];   // per-wave P tile (bf16), reused across sub-tiles
  int h = blockIdx.y;
  int b = blockIdx.x;
  int q0 = blockIdx.z * 128;
  int tid = threadIdx.x;
  int w = tid >> 6, lane = tid & 63, g = lane >> 4, lr = lane & 15;
  int qw0 = q0 + w * 16;
  size_t headoff = (size_t)(b * Hn + h) * Tn * DHn;
  bf16x8 qf0 = *(const bf16x8*)&Qb[headoff + (size_t)(qw0 + lr)*64 + g*8];
  bf16x8 qf1 = *(const bf16x8*)&Qb[headoff + (size_t)(qw0 + lr)*64 + 32 + g*8];
  f32x4 O[4] = {};
  f32x4 Os = {0.f, 0.f, 0.f, 0.f};
  union { u16 s[8]; bf16x8 v; } one8;
  #pragma unroll
  for (int j = 0; j < 8; j++) one8.s[j] = 0x3F80u; // bf16 1.0

  // loop-invariant skew-shuffle source lanes + register-set predicates:
  // skew(rowq,col) = REL[rowq][col-rowq+15]; producer lane = same g-group,
  // lane (lr-rowq+15)&15, register-set c (if lr<=rowq) else c+1, same reg r.
  int srcl[4]; bool psel[4];
  #pragma unroll
  for (int r = 0; r < 4; r++) {
    int rowq = g*4 + r;
    srcl[r] = (lane & 48) + ((lr - rowq + 15) & 15);
    psel[r] = (lr <= rowq);
  }
  const unsigned long long* mrow = mbits + ((size_t)(b * Tn + qw0 + g*4) << 4);

  // REL carry prologue: jt=0 window of the first tile
  f32x4 carry = {0.f, 0.f, 0.f, 0.f};
  {
    int rmin0 = 0 - qw0 + 1008;
    const u16* ep = &Eb[(size_t)(rmin0 + lr) * 64 + g*8];
    carry = mfma16(qf0, *(const bf16x8*)ep, carry);
    carry = mfma16(qf1, *(const bf16x8*)(ep + 32), carry);
  }

  // staging (512 threads, 128-kv iter):
  //   K: 128 rows x 64 cols -> rows tid>>3 and +64, chunk (tid&7)*8 (XOR-swizzled)
  //   V^T: 64 rows x 128 cols -> rows tid>>4 and +32, chunk (tid&15)*8
  int sKr = tid >> 3, sKc = (tid & 7) * 8;
  int kswz = sKc ^ ((sKr & 7) << 3);       // (sKr+64)&7 == sKr&7 -> same swizzle both rows
  int sVr = tid >> 4, sVc = (tid & 15) * 8;
  const u16* Kgs = Kb + headoff + (size_t)sKr * 64 + sKc;
  const u16* Vgs = VT + headoff + (size_t)sVr * 1024 + sVc;
  int4 kA = *(const int4*)Kgs;
  int4 kB = *(const int4*)(Kgs + (size_t)64 * 64);
  int4 vA = *(const int4*)Vgs;
  int4 vB = *(const int4*)(Vgs + 32 * 1024);

  int kread = (g * 8) ^ ((lr & 7) << 3);      // swizzled col for K fragment, low half
  int kread2 = (32 + g * 8) ^ ((lr & 7) << 3);

  for (int k0 = 0; k0 < Tn; k0 += 128) {
    __syncthreads();
    *(int4*)&KlF[sKr * 64 + kswz]        = kA;
    *(int4*)&KlF[(sKr + 64) * 64 + kswz] = kB;
    *(int4*)&Vt[sVr][sVc]                = vA;
    *(int4*)&Vt[sVr + 32][sVc]           = vB;
    __syncthreads();

    // packed mask words for both tiles (L2-hot, issued first)
    uint2 mw[2][4];
    #pragma unroll
    for (int t = 0; t < 2; t++)
      #pragma unroll
      for (int r = 0; r < 4; r++)
        mw[t][r] = *(const uint2*)(mrow + (size_t)r * 16 + (k0 >> 6) + t);

    int rmin0 = k0 - qw0 + 1008;
    bf16x8 pa00, pa01, pa10, pa11;

    // ================= sub-tile 0 =================
    f32x4 Rm0[5];
    Rm0[0] = carry;
    __builtin_amdgcn_s_setprio(1);
    #pragma unroll
    for (int jt = 1; jt < 5; jt++) {
      const u16* ep = &Eb[(size_t)(rmin0 + jt*16 + lr) * 64 + g*8];
      f32x4 R = {0.f, 0.f, 0.f, 0.f};
      R = mfma16(qf0, *(const bf16x8*)ep, R);
      R = mfma16(qf1, *(const bf16x8*)(ep + 32), R);
      Rm0[jt] = R;
    }
    f32x4 S0[4];
    #pragma unroll
    for (int c = 0; c < 4; c++) {
      int krow = c*16 + lr;
      f32x4 z = {0.f, 0.f, 0.f, 0.f};
      z = mfma16(qf0, *(const bf16x8*)&KlF[krow*64 + kread], z);
      z = mfma16(qf1, *(const bf16x8*)&KlF[krow*64 + kread2], z);
      S0[c] = z;
    }
    __builtin_amdgcn_s_setprio(0);
    {
      float sh[5][4];
      #pragma unroll
      for (int s5 = 0; s5 < 5; s5++)
        #pragma unroll
        for (int r = 0; r < 4; r++)
          sh[s5][r] = __shfl(Rm0[s5][r], srcl[r], 64);
      #pragma unroll
      for (int c = 0; c < 4; c++)
        #pragma unroll
        for (int r = 0; r < 4; r++) {
          float s = S0[c][r] + (psel[r] ? sh[c][r] : sh[c+1][r]);
          unsigned bit;
          if (c == 0)      bit = (mw[0][r].x >> lr) & 1u;
          else if (c == 1) bit = (mw[0][r].x >> (16 + lr)) & 1u;
          else if (c == 2) bit = (mw[0][r].y >> lr) & 1u;
          else             bit = (mw[0][r].y >> (16 + lr)) & 1u;
          s = bit ? -1e9f : s;
          RP[w][g*4 + r][c*16 + lr] = f2bf(__builtin_amdgcn_exp2f(s));
        }
      pa00 = *(const bf16x8*)&RP[w][lr][g*8];
      pa01 = *(const bf16x8*)&RP[w][lr][32 + g*8];
    }

    // ================= sub-tile 1: REL E-loads first =================
    f32x4 Rm1[5];
    Rm1[0] = Rm0[4];
    __builtin_amdgcn_s_setprio(1);
    #pragma unroll
    for (int jt = 1; jt < 5; jt++) {
      const u16* ep = &Eb[(size_t)(rmin0 + 64 + jt*16 + lr) * 64 + g*8];
      f32x4 R = {0.f, 0.f, 0.f, 0.f};
      R = mfma16(qf0, *(const bf16x8*)ep, R);
      R = mfma16(qf1, *(const bf16x8*)(ep + 32), R);
      Rm1[jt] = R;
    }
    __builtin_amdgcn_s_setprio(0);
    carry = Rm1[4];

    // HBM K/V prefetch for next iter: issued AFTER all L2 loads of this iter
    // (in-order vmcnt retirement -> must be youngest). sched_barrier pins it.
    __builtin_amdgcn_sched_barrier(0);
    if (k0 + 128 < Tn) {
      kA = *(const int4*)(Kgs + (size_t)(k0 + 128) * 64);
      kB = *(const int4*)(Kgs + (size_t)(k0 + 192) * 64);
      vA = *(const int4*)(Vgs + k0 + 128);
      vB = *(const int4*)(Vgs + 32 * 1024 + k0 + 128);
    }
    __builtin_amdgcn_sched_barrier(0);

    // sub-tile 1: S + softmax
    f32x4 S1[4];
    __builtin_amdgcn_s_setprio(1);
    #pragma unroll
    for (int c = 0; c < 4; c++) {
      int krow = 64 + c*16 + lr;
      f32x4 z = {0.f, 0.f, 0.f, 0.f};
      z = mfma16(qf0, *(const bf16x8*)&KlF[krow*64 + kread], z);
      z = mfma16(qf1, *(const bf16x8*)&KlF[krow*64 + kread2], z);
      S1[c] = z;
    }
    __builtin_amdgcn_s_setprio(0);
    {
      float sh[5][4];
      #pragma unroll
      for (int s5 = 0; s5 < 5; s5++)
        #pragma unroll
        for (int r = 0; r < 4; r++)
          sh[s5][r] = __shfl(Rm1[s5][r], srcl[r], 64);
      #pragma unroll
      for (int c = 0; c < 4; c++)
        #pragma unroll
        for (int r = 0; r < 4; r++) {
          float s = S1[c][r] + (psel[r] ? sh[c][r] : sh[c+1][r]);
          unsigned bit;
          if (c == 0)      bit = (mw[1][r].x >> lr) & 1u;
          else if (c == 1) bit = (mw[1][r].x >> (16 + lr)) & 1u;
          else if (c == 2) bit = (mw[1][r].y >> lr) & 1u;
          else             bit = (mw[1][r].y >> (16 + lr)) & 1u;
          s = bit ? -1e9f : s;
          RP[w][g*4 + r][c*16 + lr] = f2bf(__builtin_amdgcn_exp2f(s));
        }
      pa10 = *(const bf16x8*)&RP[w][lr][g*8];
      pa11 = *(const bf16x8*)&RP[w][lr][32 + g*8];
    }

    // ================= PV + row-sum (LDS + MFMA only) =================
    __builtin_amdgcn_s_setprio(1);
    #pragma unroll
    for (int ct = 0; ct < 4; ct++) {
      bf16x8 vf0 = *(const bf16x8*)&Vt[ct*16 + lr][g*8];
      bf16x8 vf1 = *(const bf16x8*)&Vt[ct*16 + lr][32 + g*8];
      O[ct] = mfma16(pa00, vf0, O[ct]);
      O[ct] = mfma16(pa01, vf1, O[ct]);
      bf16x8 vf2 = *(const bf16x8*)&Vt[ct*16 + lr][64 + g*8];
      bf16x8 vf3 = *(const bf16x8*)&Vt[ct*16 + lr][96 + g*8];
      O[ct] = mfma16(pa10, vf2, O[ct]);
      O[ct] = mfma16(pa11, vf3, O[ct]);
    }
    Os = mfma16(pa00, one8.v, Os);
    Os = mfma16(pa01, one8.v, Os);
    Os = mfma16(pa10, one8.v, Os);
    Os = mfma16(pa11, one8.v, Os);
    __builtin_amdgcn_s_setprio(0);
  }
  // normalized ctx write (no split -> no combine pass)
  float inv[4];
  #pragma unroll
  for (int r = 0; r < 4; r++) inv[r] = 1.f / Os[r];
  #pragma unroll
  for (int ct = 0; ct < 4; ct++)
    #pragma unroll
    for (int r = 0; r < 4; r++) {
      int rowq = g*4 + r, col = ct*16 + lr;
      ctx[(size_t)(b*Tn + qw0 + rowq) * 1024 + h*64 + col] = f2bf(O[ct][r] * inv[r]);
    }
}

// ---------------- residual + LayerNorm ----------------
__global__ __launch_bounds__(256) void k_ln(const float* __restrict__ x, const u16* __restrict__ o,
                                            const float* __restrict__ gamma, const float* __restrict__ beta,
                                            float* __restrict__ out) {
  int m = blockIdx.x, tid = threadIdx.x;
  int w = tid >> 6, lane = tid & 63;
  const float* xr = x + (size_t)m * Dn;
  const u16* orow = o + (size_t)m * Dn;
  float4 xv = *(const float4*)&xr[tid*4];
  union { uint2 u; u16 s[4]; } ou;
  ou.u = *(const uint2*)&orow[tid*4];
  float y[4];
  y[0] = xv.x + bf2f(ou.s[0]);
  y[1] = xv.y + bf2f(ou.s[1]);
  y[2] = xv.z + bf2f(ou.s[2]);
  y[3] = xv.w + bf2f(ou.s[3]);
  float s = y[0]+y[1]+y[2]+y[3];
  float s2 = y[0]*y[0]+y[1]*y[1]+y[2]*y[2]+y[3]*y[3];
  #pragma unroll
  for (int off = 1; off < 64; off <<= 1) { s += __shfl_xor(s, off); s2 += __shfl_xor(s2, off); }
  __shared__ float red[8];
  if (lane == 0) { red[w] = s; red[4 + w] = s2; }
  __syncthreads();
  float Sa = red[0]+red[1]+red[2]+red[3];
  float Sb = red[4]+red[5]+red[6]+red[7];
  float mu = Sa * (1.f/1024.f);
  float var = Sb * (1.f/1024.f) - mu*mu;
  float rstd = rsqrtf(var + 1e-5f);
  #pragma unroll
  for (int i = 0; i < 4; i++) {
    int j = tid*4 + i;
    out[(size_t)m*Dn + j] = (y[i] - mu) * rstd * gamma[j] + beta[j];
  }
}

extern "C" void kernel_launch(void* const* d_in, const int* in_sizes, int n_in,
                              void* d_out, int out_size, void* d_ws, size_t ws_size,
                              hipStream_t stream) {
  const float* x    = (const float*)d_in[0];
  const float* ctxI = (const float*)d_in[1];
  const unsigned char* mask = (const unsigned char*)d_in[2];
  const float* lut  = (const float*)d_in[3];
  const float* Wq   = (const float*)d_in[4];
  const float* Wk   = (const float*)d_in[5];
  const float* Wv   = (const float*)d_in[6];
  const float* Wo   = (const float*)d_in[7];
  const float* bo   = (const float*)d_in[8];
  const float* gamma= (const float*)d_in[9];
  const float* beta = (const float*)d_in[10];
  float* out = (float*)d_out;

  u16* WqT  = (u16*)d_ws;
  u16* WkT  = WqT + 1048576;
  u16* WvT  = WkT + 1048576;   // contiguous with WkT -> fused KV GEMM reads [2048][1024]
  u16* WoT  = WvT + 1048576;
  u16* Ebf  = WoT + 1048576;
  u16* Qbf  = Ebf + 131072;
  u16* Kbf  = Qbf + 4194304;
  u16* Vbf  = Kbf + 4194304;   // holds V^T [B,H,DH,T]
  u16* ctxb = Vbf + 4194304;
  u16* obf  = ctxb + 4194304;
  unsigned long long* mbits = (unsigned long long*)(obf + 4194304); // 65536 words = 512 KB

  k_maskpack<<<16384, 256, 0, stream>>>(mask, mbits);
  k_convert<<<128, 256, 0, stream>>>(lut, Ebf, 131008);
  dim3 tb(32, 8), tg(32, 32);
  k_transpose_convert<<<tg, tb, 0, stream>>>(Wq, WqT);
  k_transpose_convert<<<tg, tb, 0, stream>>>(Wk, WkT);
  k_transpose_convert<<<tg, tb, 0, stream>>>(Wv, WvT);
  k_transpose_convert<<<tg, tb, 0, stream>>>(Wo, WoT);
  k_proj<<<768, 256, 0, stream>>>(x, ctxI, WqT, WkT, Qbf, Kbf, Vbf);
  k_attn<<<dim3(4, 16, 8), 512, 0, stream>>>(Qbf, Kbf, Vbf, Ebf, mbits, ctxb);
  k_gemm_bt<<<dim3(8, 32), 256, 0, stream>>>(ctxb, WoT, obf, bo);
  k_ln<<<4096, 256, 0, stream>>>(x, obf, gamma, beta, out);
}

// Round 9
// 164.723 us; speedup vs baseline: 1.2839x; 1.1505x over previous
//
#include <hip/hip_runtime.h>

#define Tn 1024
#define Hn 16
#define Dn 1024
#define DHn 64
// SCALE * log2(e): Q is pre-scaled by this, softmax then uses exp2 directly.
#define QSCALE 0.18033688011112042f

typedef unsigned short u16;
typedef unsigned long long ull;
typedef __bf16 bf16x8 __attribute__((ext_vector_type(8)));
typedef float f32x4 __attribute__((ext_vector_type(4)));

__device__ __forceinline__ u16 f2bf(float f) {
  union { float f; unsigned u; } v; v.f = f;
  return (u16)((v.u + 0x7FFFu + ((v.u >> 16) & 1u)) >> 16);
}
__device__ __forceinline__ float bf2f(u16 s) {
  union { unsigned u; float f; } v; v.u = ((unsigned)s) << 16;
  return v.f;
}
__device__ __forceinline__ f32x4 mfma16(bf16x8 a, bf16x8 b, f32x4 c) {
  return __builtin_amdgcn_mfma_f32_16x16x32_bf16(a, b, c, 0, 0, 0);
}

// ---------------- convert fp32 -> bf16 (linear) ----------------
__global__ void k_convert(const float* __restrict__ src, u16* __restrict__ dst, int n) {
  int i = (blockIdx.x * blockDim.x + threadIdx.x) * 4;
  if (i >= n) return;
  float4 v = *(const float4*)(src + i);
  union { u16 s[4]; uint2 u; } o;
  o.s[0] = f2bf(v.x); o.s[1] = f2bf(v.y); o.s[2] = f2bf(v.z); o.s[3] = f2bf(v.w);
  *(uint2*)(dst + i) = o.u;
}

// ---------------- pack bool mask bytes -> 64-bit words (bit k = mask[base+k]) ----------------
__global__ __launch_bounds__(256) void k_maskpack(const unsigned char* __restrict__ m,
                                                  unsigned long long* __restrict__ mb) {
  int wi = blockIdx.x * 4 + (threadIdx.x >> 6);
  int lane = threadIdx.x & 63;
  unsigned char v = m[((size_t)wi << 6) + lane];
  unsigned long long bal = __ballot(v != 0);
  if (lane == 0) mb[wi] = bal;
}

// ---------------- transpose + convert: W[K][N] fp32 -> Wt[N][K] bf16 ----------------
__global__ void k_transpose_convert(const float* __restrict__ W, u16* __restrict__ Wt) {
  __shared__ float tile[32][33];
  int n0 = blockIdx.x * 32, k0 = blockIdx.y * 32;
  int tx = threadIdx.x, ty = threadIdx.y; // (32,8)
  #pragma unroll
  for (int i = 0; i < 4; i++)
    tile[ty + 8*i][tx] = W[(size_t)(k0 + ty + 8*i) * Dn + n0 + tx];
  __syncthreads();
  #pragma unroll
  for (int i = 0; i < 4; i++)
    Wt[(size_t)(n0 + ty + 8*i) * Dn + k0 + tx] = f2bf(tile[tx][ty + 8*i]);
}

// ---------------- merged Q/KV projection GEMM, fp32 A with in-staging convert ----------------
__global__ __launch_bounds__(256) void k_proj(const float* __restrict__ x, const float* __restrict__ ctxI,
                                              const u16* __restrict__ WqT, const u16* __restrict__ WkvT,
                                              u16* __restrict__ Qb, u16* __restrict__ Kb, u16* __restrict__ Vb) {
  __shared__ __align__(16) u16 Al[128][40];
  __shared__ __align__(16) u16 Bl[128][40];
  int bx = blockIdx.x;
  bool isQ = bx < 256;
  int idx = isQ ? bx : bx - 256;
  int m0 = (idx & 31) * 128;
  int n0 = (idx >> 5) * 128;
  const float* A = isQ ? x : ctxI;
  const u16* Bt = isQ ? WqT : WkvT;
  u16* dst0 = isQ ? Qb : Kb;
  float scale = isQ ? QSCALE : 1.0f;
  int tid = threadIdx.x;
  int w = tid >> 6, lane = tid & 63, g = lane >> 4, lr = lane & 15;
  int wr = w >> 1, wc = w & 1;
  f32x4 acc[4][4] = {};
  int sr = tid >> 2, sc = tid & 3;
  const float* Ap0 = &A[(size_t)(m0 + sr) * Dn + sc * 8];
  const float* Ap1 = Ap0 + (size_t)64 * Dn;
  const u16* Bp0 = &Bt[(size_t)(n0 + sr) * Dn + sc * 8];
  const u16* Bp1 = Bp0 + (size_t)64 * Dn;
  float4 ra0a = *(const float4*)Ap0, ra0b = *(const float4*)(Ap0 + 4);
  float4 ra1a = *(const float4*)Ap1, ra1b = *(const float4*)(Ap1 + 4);
  int4 rb0 = *(const int4*)Bp0;
  int4 rb1 = *(const int4*)Bp1;
  for (int k0 = 0; k0 < Dn; k0 += 32) {
    __syncthreads();
    {
      union { u16 s[8]; int4 v; } c0, c1;
      c0.s[0]=f2bf(ra0a.x); c0.s[1]=f2bf(ra0a.y); c0.s[2]=f2bf(ra0a.z); c0.s[3]=f2bf(ra0a.w);
      c0.s[4]=f2bf(ra0b.x); c0.s[5]=f2bf(ra0b.y); c0.s[6]=f2bf(ra0b.z); c0.s[7]=f2bf(ra0b.w);
      c1.s[0]=f2bf(ra1a.x); c1.s[1]=f2bf(ra1a.y); c1.s[2]=f2bf(ra1a.z); c1.s[3]=f2bf(ra1a.w);
      c1.s[4]=f2bf(ra1b.x); c1.s[5]=f2bf(ra1b.y); c1.s[6]=f2bf(ra1b.z); c1.s[7]=f2bf(ra1b.w);
      *(int4*)&Al[sr][sc*8]      = c0.v;
      *(int4*)&Al[sr + 64][sc*8] = c1.v;
    }
    *(int4*)&Bl[sr][sc*8]      = rb0;
    *(int4*)&Bl[sr + 64][sc*8] = rb1;
    __syncthreads();
    if (k0 + 32 < Dn) {
      ra0a = *(const float4*)(Ap0 + k0 + 32); ra0b = *(const float4*)(Ap0 + k0 + 36);
      ra1a = *(const float4*)(Ap1 + k0 + 32); ra1b = *(const float4*)(Ap1 + k0 + 36);
      rb0 = *(const int4*)(Bp0 + k0 + 32);
      rb1 = *(const int4*)(Bp1 + k0 + 32);
    }
    bf16x8 a[4], b[4];
    #pragma unroll
    for (int mi = 0; mi < 4; mi++) a[mi] = *(const bf16x8*)&Al[wr*64 + mi*16 + lr][g*8];
    #pragma unroll
    for (int ni = 0; ni < 4; ni++) b[ni] = *(const bf16x8*)&Bl[wc*64 + ni*16 + lr][g*8];
    #pragma unroll
    for (int mi = 0; mi < 4; mi++)
      #pragma unroll
      for (int ni = 0; ni < 4; ni++)
        acc[mi][ni] = mfma16(a[mi], b[ni], acc[mi][ni]);
  }
  #pragma unroll
  for (int mi = 0; mi < 4; mi++)
    #pragma unroll
    for (int ni = 0; ni < 4; ni++) {
      int row0 = m0 + wr*64 + mi*16 + g*4;
      int col = n0 + wc*64 + ni*16 + lr;
      int bb = row0 >> 10, tt0 = row0 & 1023;
      int hh = col >> 6, dd = col & 63;
      if (hh < 16) {
        u16* p = dst0 + (((size_t)(bb*16 + hh) << 10) + (size_t)tt0) * 64 + dd;
        #pragma unroll
        for (int r = 0; r < 4; r++) p[(size_t)r * 64] = f2bf(acc[mi][ni][r] * scale);
      } else {
        union { u16 s[4]; uint2 u; } o;
        #pragma unroll
        for (int r = 0; r < 4; r++) o.s[r] = f2bf(acc[mi][ni][r]);
        *(uint2*)(Vb + (((size_t)((bb*16 + (hh - 16)) * 64 + dd)) << 10) + tt0) = o.u;
      }
    }
}

// ---------------- O-projection GEMM: bf16 A, linear write + fp32 bias ----------------
__global__ __launch_bounds__(256) void k_gemm_bt(const u16* __restrict__ A, const u16* __restrict__ Bt,
                                                 u16* __restrict__ dst0, const float* __restrict__ bias) {
  __shared__ __align__(16) u16 Al[128][40];
  __shared__ __align__(16) u16 Bl[128][40];
  int m0 = blockIdx.y * 128, n0 = blockIdx.x * 128;
  int tid = threadIdx.x;
  int w = tid >> 6, lane = tid & 63, g = lane >> 4, lr = lane & 15;
  int wr = w >> 1, wc = w & 1;
  f32x4 acc[4][4] = {};
  int sr = tid >> 2, sc = tid & 3;
  const u16* Ap0 = &A[(size_t)(m0 + sr) * Dn + sc * 8];
  const u16* Ap1 = &A[(size_t)(m0 + sr + 64) * Dn + sc * 8];
  const u16* Bp0 = &Bt[(size_t)(n0 + sr) * Dn + sc * 8];
  const u16* Bp1 = &Bt[(size_t)(n0 + sr + 64) * Dn + sc * 8];
  int4 ra0 = *(const int4*)Ap0;
  int4 ra1 = *(const int4*)Ap1;
  int4 rb0 = *(const int4*)Bp0;
  int4 rb1 = *(const int4*)Bp1;
  for (int k0 = 0; k0 < Dn; k0 += 32) {
    __syncthreads();
    *(int4*)&Al[sr][sc*8]      = ra0;
    *(int4*)&Al[sr + 64][sc*8] = ra1;
    *(int4*)&Bl[sr][sc*8]      = rb0;
    *(int4*)&Bl[sr + 64][sc*8] = rb1;
    __syncthreads();
    if (k0 + 32 < Dn) {
      ra0 = *(const int4*)(Ap0 + k0 + 32);
      ra1 = *(const int4*)(Ap1 + k0 + 32);
      rb0 = *(const int4*)(Bp0 + k0 + 32);
      rb1 = *(const int4*)(Bp1 + k0 + 32);
    }
    bf16x8 a[4], b[4];
    #pragma unroll
    for (int mi = 0; mi < 4; mi++) a[mi] = *(const bf16x8*)&Al[wr*64 + mi*16 + lr][g*8];
    #pragma unroll
    for (int ni = 0; ni < 4; ni++) b[ni] = *(const bf16x8*)&Bl[wc*64 + ni*16 + lr][g*8];
    #pragma unroll
    for (int mi = 0; mi < 4; mi++)
      #pragma unroll
      for (int ni = 0; ni < 4; ni++)
        acc[mi][ni] = mfma16(a[mi], b[ni], acc[mi][ni]);
  }
  #pragma unroll
  for (int mi = 0; mi < 4; mi++)
    #pragma unroll
    for (int ni = 0; ni < 4; ni++) {
      int row0 = m0 + wr*64 + mi*16 + g*4;
      int col = n0 + wc*64 + ni*16 + lr;
      #pragma unroll
      for (int r = 0; r < 4; r++)
        dst0[(size_t)(row0 + r) * Dn + col] = f2bf(acc[mi][ni][r] + bias[col]);
    }
}

// ---------------- flash attention with Music-Transformer skew ----------------
// grid (B, H, T/256), block 512 = 8 waves; wave w owns 32 q-rows (two 16-row
// halves h0/h1). K/V fragments and the LDS tile are shared by both halves, so
// per-q-row staging/barrier/ds_read cost HALVES vs QBLK=16, and the two halves
// give 2x independent chains per wave (ILP). REL E-loads are shared: half1's
// windows overlap half0's by 48/64 rows (10 pair-loads/iter for 32 rows).
// Load-order discipline (r6): mask+E (L2) issued BEFORE the HBM K/V prefetch.
// Fixed-max softmax, ones-MFMA row-sum, per-half REL carry chains.
__global__ __launch_bounds__(512, 2) void k_attn(const u16* __restrict__ Qb, const u16* __restrict__ Kb,
                                              const u16* __restrict__ VT, const u16* __restrict__ Eb,
                                              const unsigned long long* __restrict__ mbits,
                                              u16* __restrict__ ctx) {
  __shared__ __align__(16) u16 KlF[128 * 64];   // XOR-swizzled: u16 idx = row*64 + (col ^ ((row&7)<<3))
  __shared__ __align__(16) u16 Vt[64][136];     // V^T tile: Vt[d][kv-local 0..127]
  __shared__ __align__(16) u16 RP[8][16][72];   // per-wave P tile (bf16), reused across sub-tiles/halves
  int h = blockIdx.y;
  int b = blockIdx.x;
  int q0 = blockIdx.z * 256;
  int tid = threadIdx.x;
  int w = tid >> 6, lane = tid & 63, g = lane >> 4, lr = lane & 15;
  int qw0 = q0 + w * 32;                        // h0: qw0..+15, h1: qw0+16..+31
  size_t headoff = (size_t)(b * Hn + h) * Tn * DHn;
  bf16x8 qf0 = *(const bf16x8*)&Qb[headoff + (size_t)(qw0 + lr)*64 + g*8];
  bf16x8 qf1 = *(const bf16x8*)&Qb[headoff + (size_t)(qw0 + lr)*64 + 32 + g*8];
  bf16x8 qf2 = *(const bf16x8*)&Qb[headoff + (size_t)(qw0 + 16 + lr)*64 + g*8];
  bf16x8 qf3 = *(const bf16x8*)&Qb[headoff + (size_t)(qw0 + 16 + lr)*64 + 32 + g*8];
  f32x4 O[8] = {};
  f32x4 Os0 = {0.f, 0.f, 0.f, 0.f}, Os1 = {0.f, 0.f, 0.f, 0.f};
  union { u16 s[8]; bf16x8 v; } one8;
  #pragma unroll
  for (int j = 0; j < 8; j++) one8.s[j] = 0x3F80u; // bf16 1.0

  // loop-invariant skew-shuffle source lanes + register-set predicates
  // (identical for both halves: rowq is the row index WITHIN the 16-row half)
  int srcl[4]; bool psel[4];
  #pragma unroll
  for (int r = 0; r < 4; r++) {
    int rowq = g*4 + r;
    srcl[r] = (lane & 48) + ((lr - rowq + 15) & 15);
    psel[r] = (lr <= rowq);
  }
  const unsigned long long* mrow = mbits + ((size_t)(b * Tn + qw0 + g*4) << 4); // h1: +256 words

  // REL carry prologues: h0 window (1008-qw0), h1 window (1008-qw0-16)
  f32x4 carry0 = {0.f, 0.f, 0.f, 0.f}, carry1 = {0.f, 0.f, 0.f, 0.f};
  {
    int rm = 1008 - qw0;
    const u16* ep = &Eb[(size_t)(rm + lr) * 64 + g*8];
    carry0 = mfma16(qf0, *(const bf16x8*)ep, carry0);
    carry0 = mfma16(qf1, *(const bf16x8*)(ep + 32), carry0);
    const u16* ep1 = &Eb[(size_t)(rm - 16 + lr) * 64 + g*8];
    carry1 = mfma16(qf2, *(const bf16x8*)ep1, carry1);
    carry1 = mfma16(qf3, *(const bf16x8*)(ep1 + 32), carry1);
  }

  // staging (512 threads, 128-kv iter) — unchanged tile geometry
  int sKr = tid >> 3, sKc = (tid & 7) * 8;
  int kswz = sKc ^ ((sKr & 7) << 3);
  int sVr = tid >> 4, sVc = (tid & 15) * 8;
  const u16* Kgs = Kb + headoff + (size_t)sKr * 64 + sKc;
  const u16* Vgs = VT + headoff + (size_t)sVr * 1024 + sVc;
  int4 kA = *(const int4*)Kgs;
  int4 kB = *(const int4*)(Kgs + (size_t)64 * 64);
  int4 vA = *(const int4*)Vgs;
  int4 vB = *(const int4*)(Vgs + 32 * 1024);

  int kread = (g * 8) ^ ((lr & 7) << 3);
  int kread2 = (32 + g * 8) ^ ((lr & 7) << 3);

  for (int k0 = 0; k0 < Tn; k0 += 128) {
    __syncthreads();
    *(int4*)&KlF[sKr * 64 + kswz]        = kA;
    *(int4*)&KlF[(sKr + 64) * 64 + kswz] = kB;
    *(int4*)&Vt[sVr][sVc]                = vA;
    *(int4*)&Vt[sVr + 32][sVc]           = vB;
    __syncthreads();

    // packed mask words, both tiles x both halves (L2-hot, issued first)
    uint2 mw0[2][4], mw1[2][4];
    #pragma unroll
    for (int t = 0; t < 2; t++)
      #pragma unroll
      for (int r = 0; r < 4; r++) {
        mw0[t][r] = *(const uint2*)(mrow + (size_t)r * 16 + (k0 >> 6) + t);
        mw1[t][r] = *(const uint2*)(mrow + 256 + (size_t)r * 16 + (k0 >> 6) + t);
      }

    int rmin0 = k0 - qw0 + 1008;
    bf16x8 pa000, pa001, pa010, pa011;   // sub-tile 0: h0, h1
    bf16x8 pa100, pa101, pa110, pa111;   // sub-tile 1: h0, h1

    // ================= sub-tile 0 =================
    // shared E windows e[j] = rows rmin0 + 16j (j=0..4):
    //   h0 uses e[1..4] (its jt=1..4), e-carry covers jt=0
    //   h1 uses e[0..3] (its jt=1..4), its carry covers jt=0
    bf16x8 e0[5][2];
    #pragma unroll
    for (int j = 0; j < 5; j++) {
      const u16* ep = &Eb[(size_t)(rmin0 + j*16 + lr) * 64 + g*8];
      e0[j][0] = *(const bf16x8*)ep;
      e0[j][1] = *(const bf16x8*)(ep + 32);
    }
    f32x4 Rm0[5], Rn0[5];
    Rm0[0] = carry0;
    Rn0[0] = carry1;
    __builtin_amdgcn_s_setprio(1);
    #pragma unroll
    for (int j = 1; j < 5; j++) {
      f32x4 R = {0.f, 0.f, 0.f, 0.f};
      R = mfma16(qf0, e0[j][0], R);
      R = mfma16(qf1, e0[j][1], R);
      Rm0[j] = R;
      f32x4 R2 = {0.f, 0.f, 0.f, 0.f};
      R2 = mfma16(qf2, e0[j-1][0], R2);
      R2 = mfma16(qf3, e0[j-1][1], R2);
      Rn0[j] = R2;
    }
    f32x4 S0[4], T0[4];
    #pragma unroll
    for (int c = 0; c < 4; c++) {
      int krow = c*16 + lr;
      bf16x8 kf0 = *(const bf16x8*)&KlF[krow*64 + kread];
      bf16x8 kf1 = *(const bf16x8*)&KlF[krow*64 + kread2];
      f32x4 z = {0.f, 0.f, 0.f, 0.f};
      z = mfma16(qf0, kf0, z); z = mfma16(qf1, kf1, z);
      S0[c] = z;
      f32x4 z2 = {0.f, 0.f, 0.f, 0.f};
      z2 = mfma16(qf2, kf0, z2); z2 = mfma16(qf3, kf1, z2);
      T0[c] = z2;
    }
    __builtin_amdgcn_s_setprio(0);
    {
      float sh[5][4], si[5][4];
      #pragma unroll
      for (int s5 = 0; s5 < 5; s5++)
        #pragma unroll
        for (int r = 0; r < 4; r++) {
          sh[s5][r] = __shfl(Rm0[s5][r], srcl[r], 64);
          si[s5][r] = __shfl(Rn0[s5][r], srcl[r], 64);
        }
      #pragma unroll
      for (int c = 0; c < 4; c++)
        #pragma unroll
        for (int r = 0; r < 4; r++) {
          float s = S0[c][r] + (psel[r] ? sh[c][r] : sh[c+1][r]);
          unsigned bit;
          if (c == 0)      bit = (mw0[0][r].x >> lr) & 1u;
          else if (c == 1) bit = (mw0[0][r].x >> (16 + lr)) & 1u;
          else if (c == 2) bit = (mw0[0][r].y >> lr) & 1u;
          else             bit = (mw0[0][r].y >> (16 + lr)) & 1u;
          s = bit ? -1e9f : s;
          RP[w][g*4 + r][c*16 + lr] = f2bf(__builtin_amdgcn_exp2f(s));
        }
      pa000 = *(const bf16x8*)&RP[w][lr][g*8];
      pa001 = *(const bf16x8*)&RP[w][lr][32 + g*8];
      #pragma unroll
      for (int c = 0; c < 4; c++)
        #pragma unroll
        for (int r = 0; r < 4; r++) {
          float s = T0[c][r] + (psel[r] ? si[c][r] : si[c+1][r]);
          unsigned bit;
          if (c == 0)      bit = (mw1[0][r].x >> lr) & 1u;
          else if (c == 1) bit = (mw1[0][r].x >> (16 + lr)) & 1u;
          else if (c == 2) bit = (mw1[0][r].y >> lr) & 1u;
          else             bit = (mw1[0][r].y >> (16 + lr)) & 1u;
          s = bit ? -1e9f : s;
          RP[w][g*4 + r][c*16 + lr] = f2bf(__builtin_amdgcn_exp2f(s));
        }
      pa010 = *(const bf16x8*)&RP[w][lr][g*8];
      pa011 = *(const bf16x8*)&RP[w][lr][32 + g*8];
    }

    // ================= sub-tile 1: E loads first =================
    bf16x8 e1[5][2];
    #pragma unroll
    for (int j = 0; j < 5; j++) {
      const u16* ep = &Eb[(size_t)(rmin0 + 64 + j*16 + lr) * 64 + g*8];
      e1[j][0] = *(const bf16x8*)ep;
      e1[j][1] = *(const bf16x8*)(ep + 32);
    }
    f32x4 Rm1[5], Rn1[5];
    Rm1[0] = Rm0[4];   // h0: window rmin0+64
    Rn1[0] = Rn0[4];   // h1: window rmin0+48 (= its rmin1+64)
    __builtin_amdgcn_s_setprio(1);
    #pragma unroll
    for (int j = 1; j < 5; j++) {
      f32x4 R = {0.f, 0.f, 0.f, 0.f};
      R = mfma16(qf0, e1[j][0], R);
      R = mfma16(qf1, e1[j][1], R);
      Rm1[j] = R;
      f32x4 R2 = {0.f, 0.f, 0.f, 0.f};
      R2 = mfma16(qf2, e1[j-1][0], R2);
      R2 = mfma16(qf3, e1[j-1][1], R2);
      Rn1[j] = R2;
    }
    __builtin_amdgcn_s_setprio(0);
    carry0 = Rm1[4];
    carry1 = Rn1[4];

    // HBM K/V prefetch for next iter: AFTER all L2 loads (in-order vmcnt).
    __builtin_amdgcn_sched_barrier(0);
    if (k0 + 128 < Tn) {
      kA = *(const int4*)(Kgs + (size_t)(k0 + 128) * 64);
      kB = *(const int4*)(Kgs + (size_t)(k0 + 192) * 64);
      vA = *(const int4*)(Vgs + k0 + 128);
      vB = *(const int4*)(Vgs + 32 * 1024 + k0 + 128);
    }
    __builtin_amdgcn_sched_barrier(0);

    f32x4 S1[4], T1[4];
    __builtin_amdgcn_s_setprio(1);
    #pragma unroll
    for (int c = 0; c < 4; c++) {
      int krow = 64 + c*16 + lr;
      bf16x8 kf0 = *(const bf16x8*)&KlF[krow*64 + kread];
      bf16x8 kf1 = *(const bf16x8*)&KlF[krow*64 + kread2];
      f32x4 z = {0.f, 0.f, 0.f, 0.f};
      z = mfma16(qf0, kf0, z); z = mfma16(qf1, kf1, z);
      S1[c] = z;
      f32x4 z2 = {0.f, 0.f, 0.f, 0.f};
      z2 = mfma16(qf2, kf0, z2); z2 = mfma16(qf3, kf1, z2);
      T1[c] = z2;
    }
    __builtin_amdgcn_s_setprio(0);
    {
      float sh[5][4], si[5][4];
      #pragma unroll
      for (int s5 = 0; s5 < 5; s5++)
        #pragma unroll
        for (int r = 0; r < 4; r++) {
          sh[s5][r] = __shfl(Rm1[s5][r], srcl[r], 64);
          si[s5][r] = __shfl(Rn1[s5][r], srcl[r], 64);
        }
      #pragma unroll
      for (int c = 0; c < 4; c++)
        #pragma unroll
        for (int r = 0; r < 4; r++) {
          float s = S1[c][r] + (psel[r] ? sh[c][r] : sh[c+1][r]);
          unsigned bit;
          if (c == 0)      bit = (mw0[1][r].x >> lr) & 1u;
          else if (c == 1) bit = (mw0[1][r].x >> (16 + lr)) & 1u;
          else if (c == 2) bit = (mw0[1][r].y >> lr) & 1u;
          else             bit = (mw0[1][r].y >> (16 + lr)) & 1u;
          s = bit ? -1e9f : s;
          RP[w][g*4 + r][c*16 + lr] = f2bf(__builtin_amdgcn_exp2f(s));
        }
      pa100 = *(const bf16x8*)&RP[w][lr][g*8];
      pa101 = *(const bf16x8*)&RP[w][lr][32 + g*8];
      #pragma unroll
      for (int c = 0; c < 4; c++)
        #pragma unroll
        for (int r = 0; r < 4; r++) {
          float s = T1[c][r] + (psel[r] ? si[c][r] : si[c+1][r]);
          unsigned bit;
          if (c == 0)      bit = (mw1[1][r].x >> lr) & 1u;
          else if (c == 1) bit = (mw1[1][r].x >> (16 + lr)) & 1u;
          else if (c == 2) bit = (mw1[1][r].y >> lr) & 1u;
          else             bit = (mw1[1][r].y >> (16 + lr)) & 1u;
          s = bit ? -1e9f : s;
          RP[w][g*4 + r][c*16 + lr] = f2bf(__builtin_amdgcn_exp2f(s));
        }
      pa110 = *(const bf16x8*)&RP[w][lr][g*8];
      pa111 = *(const bf16x8*)&RP[w][lr][32 + g*8];
    }

    // ================= PV + row-sums: V fragments shared by both halves =====
    __builtin_amdgcn_s_setprio(1);
    #pragma unroll
    for (int ct = 0; ct < 4; ct++) {
      bf16x8 vf0 = *(const bf16x8*)&Vt[ct*16 + lr][g*8];
      bf16x8 vf1 = *(const bf16x8*)&Vt[ct*16 + lr][32 + g*8];
      bf16x8 vf2 = *(const bf16x8*)&Vt[ct*16 + lr][64 + g*8];
      bf16x8 vf3 = *(const bf16x8*)&Vt[ct*16 + lr][96 + g*8];
      O[ct] = mfma16(pa000, vf0, O[ct]);
      O[ct] = mfma16(pa001, vf1, O[ct]);
      O[ct] = mfma16(pa100, vf2, O[ct]);
      O[ct] = mfma16(pa101, vf3, O[ct]);
      O[4+ct] = mfma16(pa010, vf0, O[4+ct]);
      O[4+ct] = mfma16(pa011, vf1, O[4+ct]);
      O[4+ct] = mfma16(pa110, vf2, O[4+ct]);
      O[4+ct] = mfma16(pa111, vf3, O[4+ct]);
    }
    Os0 = mfma16(pa000, one8.v, Os0);
    Os0 = mfma16(pa001, one8.v, Os0);
    Os0 = mfma16(pa100, one8.v, Os0);
    Os0 = mfma16(pa101, one8.v, Os0);
    Os1 = mfma16(pa010, one8.v, Os1);
    Os1 = mfma16(pa011, one8.v, Os1);
    Os1 = mfma16(pa110, one8.v, Os1);
    Os1 = mfma16(pa111, one8.v, Os1);
    __builtin_amdgcn_s_setprio(0);
  }
  // normalized ctx write, both halves
  float inv0[4], inv1[4];
  #pragma unroll
  for (int r = 0; r < 4; r++) { inv0[r] = 1.f / Os0[r]; inv1[r] = 1.f / Os1[r]; }
  #pragma unroll
  for (int ct = 0; ct < 4; ct++)
    #pragma unroll
    for (int r = 0; r < 4; r++) {
      int rowq = g*4 + r, col = ct*16 + lr;
      ctx[(size_t)(b*Tn + qw0 + rowq) * 1024 + h*64 + col] = f2bf(O[ct][r] * inv0[r]);
      ctx[(size_t)(b*Tn + qw0 + 16 + rowq) * 1024 + h*64 + col] = f2bf(O[4+ct][r] * inv1[r]);
    }
}

// ---------------- residual + LayerNorm ----------------
__global__ __launch_bounds__(256) void k_ln(const float* __restrict__ x, const u16* __restrict__ o,
                                            const float* __restrict__ gamma, const float* __restrict__ beta,
                                            float* __restrict__ out) {
  int m = blockIdx.x, tid = threadIdx.x;
  int w = tid >> 6, lane = tid & 63;
  const float* xr = x + (size_t)m * Dn;
  const u16* orow = o + (size_t)m * Dn;
  float4 xv = *(const float4*)&xr[tid*4];
  union { uint2 u; u16 s[4]; } ou;
  ou.u = *(const uint2*)&orow[tid*4];
  float y[4];
  y[0] = xv.x + bf2f(ou.s[0]);
  y[1] = xv.y + bf2f(ou.s[1]);
  y[2] = xv.z + bf2f(ou.s[2]);
  y[3] = xv.w + bf2f(ou.s[3]);
  float s = y[0]+y[1]+y[2]+y[3];
  float s2 = y[0]*y[0]+y[1]*y[1]+y[2]*y[2]+y[3]*y[3];
  #pragma unroll
  for (int off = 1; off < 64; off <<= 1) { s += __shfl_xor(s, off); s2 += __shfl_xor(s2, off); }
  __shared__ float red[8];
  if (lane == 0) { red[w] = s; red[4 + w] = s2; }
  __syncthreads();
  float Sa = red[0]+red[1]+red[2]+red[3];
  float Sb = red[4]+red[5]+red[6]+red[7];
  float mu = Sa * (1.f/1024.f);
  float var = Sb * (1.f/1024.f) - mu*mu;
  float rstd = rsqrtf(var + 1e-5f);
  #pragma unroll
  for (int i = 0; i < 4; i++) {
    int j = tid*4 + i;
    out[(size_t)m*Dn + j] = (y[i] - mu) * rstd * gamma[j] + beta[j];
  }
}

extern "C" void kernel_launch(void* const* d_in, const int* in_sizes, int n_in,
                              void* d_out, int out_size, void* d_ws, size_t ws_size,
                              hipStream_t stream) {
  const float* x    = (const float*)d_in[0];
  const float* ctxI = (const float*)d_in[1];
  const unsigned char* mask = (const unsigned char*)d_in[2];
  const float* lut  = (const float*)d_in[3];
  const float* Wq   = (const float*)d_in[4];
  const float* Wk   = (const float*)d_in[5];
  const float* Wv   = (const float*)d_in[6];
  const float* Wo   = (const float*)d_in[7];
  const float* bo   = (const float*)d_in[8];
  const float* gamma= (const float*)d_in[9];
  const float* beta = (const float*)d_in[10];
  float* out = (float*)d_out;

  u16* WqT  = (u16*)d_ws;
  u16* WkT  = WqT + 1048576;
  u16* WvT  = WkT + 1048576;   // contiguous with WkT -> fused KV GEMM reads [2048][1024]
  u16* WoT  = WvT + 1048576;
  u16* Ebf  = WoT + 1048576;
  u16* Qbf  = Ebf + 131072;
  u16* Kbf  = Qbf + 4194304;
  u16* Vbf  = Kbf + 4194304;   // holds V^T [B,H,DH,T]
  u16* ctxb = Vbf + 4194304;
  u16* obf  = ctxb + 4194304;
  unsigned long long* mbits = (unsigned long long*)(obf + 4194304); // 65536 words = 512 KB

  k_maskpack<<<16384, 256, 0, stream>>>(mask, mbits);
  k_convert<<<128, 256, 0, stream>>>(lut, Ebf, 131008);
  dim3 tb(32, 8), tg(32, 32);
  k_transpose_convert<<<tg, tb, 0, stream>>>(Wq, WqT);
  k_transpose_convert<<<tg, tb, 0, stream>>>(Wk, WkT);
  k_transpose_convert<<<tg, tb, 0, stream>>>(Wv, WvT);
  k_transpose_convert<<<tg, tb, 0, stream>>>(Wo, WoT);
  k_proj<<<768, 256, 0, stream>>>(x, ctxI, WqT, WkT, Qbf, Kbf, Vbf);
  k_attn<<<dim3(4, 16, 4), 512, 0, stream>>>(Qbf, Kbf, Vbf, Ebf, mbits, ctxb);
  k_gemm_bt<<<dim3(8, 32), 256, 0, stream>>>(ctxb, WoT, obf, bo);
  k_ln<<<4096, 256, 0, stream>>>(x, obf, gamma, beta, out);
}

// Round 10
// 157.777 us; speedup vs baseline: 1.3404x; 1.0440x over previous
//
#include <hip/hip_runtime.h>

#define Tn 1024
#define Hn 16
#define Dn 1024
#define DHn 64
// SCALE * log2(e): Q is pre-scaled by this, softmax then uses exp2 directly.
#define QSCALE 0.18033688011112042f

typedef unsigned short u16;
typedef unsigned long long ull;
typedef __bf16 bf16x8 __attribute__((ext_vector_type(8)));
typedef float f32x4 __attribute__((ext_vector_type(4)));

__device__ __forceinline__ u16 f2bf(float f) {
  union { float f; unsigned u; } v; v.f = f;
  return (u16)((v.u + 0x7FFFu + ((v.u >> 16) & 1u)) >> 16);
}
__device__ __forceinline__ float bf2f(u16 s) {
  union { unsigned u; float f; } v; v.u = ((unsigned)s) << 16;
  return v.f;
}
__device__ __forceinline__ f32x4 mfma16(bf16x8 a, bf16x8 b, f32x4 c) {
  return __builtin_amdgcn_mfma_f32_16x16x32_bf16(a, b, c, 0, 0, 0);
}
// async global->LDS, 16B per lane; LDS dst must be wave-uniform (chunk base).
__device__ __forceinline__ void gload16(const u16* g, u16* l) {
  __builtin_amdgcn_global_load_lds(
      (const __attribute__((address_space(1))) void*)g,
      (__attribute__((address_space(3))) void*)l, 16, 0, 0);
}

// ---------------- convert fp32 -> bf16 (linear) ----------------
__global__ void k_convert(const float* __restrict__ src, u16* __restrict__ dst, int n) {
  int i = (blockIdx.x * blockDim.x + threadIdx.x) * 4;
  if (i >= n) return;
  float4 v = *(const float4*)(src + i);
  union { u16 s[4]; uint2 u; } o;
  o.s[0] = f2bf(v.x); o.s[1] = f2bf(v.y); o.s[2] = f2bf(v.z); o.s[3] = f2bf(v.w);
  *(uint2*)(dst + i) = o.u;
}

// ---------------- pack bool mask bytes -> 64-bit words (bit k = mask[base+k]) ----------------
__global__ __launch_bounds__(256) void k_maskpack(const unsigned char* __restrict__ m,
                                                  unsigned long long* __restrict__ mb) {
  int wi = blockIdx.x * 4 + (threadIdx.x >> 6);
  int lane = threadIdx.x & 63;
  unsigned char v = m[((size_t)wi << 6) + lane];
  unsigned long long bal = __ballot(v != 0);
  if (lane == 0) mb[wi] = bal;
}

// ---------------- transpose + convert x4: W[K][N] fp32 -> Wt[N][K] bf16 ----------------
__global__ void k_transpose_convert4(const float* __restrict__ W0, const float* __restrict__ W1,
                                     const float* __restrict__ W2, const float* __restrict__ W3,
                                     u16* __restrict__ T0, u16* __restrict__ T1,
                                     u16* __restrict__ T2, u16* __restrict__ T3) {
  __shared__ float tile[32][33];
  int z = blockIdx.z;
  const float* W = (z == 0) ? W0 : (z == 1) ? W1 : (z == 2) ? W2 : W3;
  u16* Wt = (z == 0) ? T0 : (z == 1) ? T1 : (z == 2) ? T2 : T3;
  int n0 = blockIdx.x * 32, k0 = blockIdx.y * 32;
  int tx = threadIdx.x, ty = threadIdx.y; // (32,8)
  #pragma unroll
  for (int i = 0; i < 4; i++)
    tile[ty + 8*i][tx] = W[(size_t)(k0 + ty + 8*i) * Dn + n0 + tx];
  __syncthreads();
  #pragma unroll
  for (int i = 0; i < 4; i++)
    Wt[(size_t)(n0 + ty + 8*i) * Dn + k0 + tx] = f2bf(tile[tx][ty + 8*i]);
}

// ---------------- merged Q/KV projection GEMM ----------------
// A fp32 reg-staged+converted (padded LDS); B bf16 via double-buffered
// global_load_lds (linear LDS). ONE barrier per K-step: STAGE(next) issues
// first, compute(cur), barrier drains -> next-tile loads fly under compute.
__global__ __launch_bounds__(256) void k_proj(const float* __restrict__ x, const float* __restrict__ ctxI,
                                              const u16* __restrict__ WqT, const u16* __restrict__ WkvT,
                                              u16* __restrict__ Qb, u16* __restrict__ Kb, u16* __restrict__ Vb) {
  __shared__ __align__(16) u16 AlP[2][128][40];
  __shared__ __align__(16) u16 BlL[2][128 * 32];
  int bx = blockIdx.x;
  bool isQ = bx < 256;
  int idx = isQ ? bx : bx - 256;
  int m0 = (idx & 31) * 128;
  int n0 = (idx >> 5) * 128;
  const float* A = isQ ? x : ctxI;
  const u16* Bt = isQ ? WqT : WkvT;
  u16* dst0 = isQ ? Qb : Kb;
  float scale = isQ ? QSCALE : 1.0f;
  int tid = threadIdx.x;
  int w = tid >> 6, lane = tid & 63, g = lane >> 4, lr = lane & 15;
  int wr = w >> 1, wc = w & 1;
  f32x4 acc[4][4] = {};
  // A staging (fp32 -> bf16): thread covers rows sr, sr+64, colseg sc*8
  int sr = tid >> 2, sc = tid & 3;
  const float* Ap0 = &A[(size_t)(m0 + sr) * Dn + sc * 8];
  const float* Ap1 = Ap0 + (size_t)64 * Dn;
  // B gload mapping: wave w stages 1KB chunks w and w+4 (16 rows x 32 cols each);
  // lane l -> row chunk*16 + l/4, colseg (l&3)*8.
  int srow = lane >> 2, scol = (lane & 3) * 8;
  const u16* Bg0 = &Bt[(size_t)(n0 + w * 16 + srow) * Dn + scol];
  const u16* Bg1 = &Bt[(size_t)(n0 + (w + 4) * 16 + srow) * Dn + scol];

  float4 a0a = *(const float4*)Ap0, a0b = *(const float4*)(Ap0 + 4);
  float4 a1a = *(const float4*)Ap1, a1b = *(const float4*)(Ap1 + 4);
  // prologue: stage tile 0 (A write + B gload), issue A-regs for tile 1
  gload16(Bg0, &BlL[0][(size_t)w * 512]);
  gload16(Bg1, &BlL[0][(size_t)(w + 4) * 512]);
  {
    union { u16 s[8]; int4 v; } c0, c1;
    c0.s[0]=f2bf(a0a.x); c0.s[1]=f2bf(a0a.y); c0.s[2]=f2bf(a0a.z); c0.s[3]=f2bf(a0a.w);
    c0.s[4]=f2bf(a0b.x); c0.s[5]=f2bf(a0b.y); c0.s[6]=f2bf(a0b.z); c0.s[7]=f2bf(a0b.w);
    c1.s[0]=f2bf(a1a.x); c1.s[1]=f2bf(a1a.y); c1.s[2]=f2bf(a1a.z); c1.s[3]=f2bf(a1a.w);
    c1.s[4]=f2bf(a1b.x); c1.s[5]=f2bf(a1b.y); c1.s[6]=f2bf(a1b.z); c1.s[7]=f2bf(a1b.w);
    *(int4*)&AlP[0][sr][sc*8]      = c0.v;
    *(int4*)&AlP[0][sr + 64][sc*8] = c1.v;
  }
  a0a = *(const float4*)(Ap0 + 32); a0b = *(const float4*)(Ap0 + 36);
  a1a = *(const float4*)(Ap1 + 32); a1b = *(const float4*)(Ap1 + 36);
  __syncthreads();

  for (int t = 0; t < 32; t++) {
    int cur = t & 1;
    if (t + 1 < 32) {
      int kn = (t + 1) * 32;
      gload16(Bg0 + kn, &BlL[cur ^ 1][(size_t)w * 512]);
      gload16(Bg1 + kn, &BlL[cur ^ 1][(size_t)(w + 4) * 512]);
      union { u16 s[8]; int4 v; } c0, c1;
      c0.s[0]=f2bf(a0a.x); c0.s[1]=f2bf(a0a.y); c0.s[2]=f2bf(a0a.z); c0.s[3]=f2bf(a0a.w);
      c0.s[4]=f2bf(a0b.x); c0.s[5]=f2bf(a0b.y); c0.s[6]=f2bf(a0b.z); c0.s[7]=f2bf(a0b.w);
      c1.s[0]=f2bf(a1a.x); c1.s[1]=f2bf(a1a.y); c1.s[2]=f2bf(a1a.z); c1.s[3]=f2bf(a1a.w);
      c1.s[4]=f2bf(a1b.x); c1.s[5]=f2bf(a1b.y); c1.s[6]=f2bf(a1b.z); c1.s[7]=f2bf(a1b.w);
      *(int4*)&AlP[cur ^ 1][sr][sc*8]      = c0.v;
      *(int4*)&AlP[cur ^ 1][sr + 64][sc*8] = c1.v;
      if (t + 2 < 32) {
        int kf = (t + 2) * 32;
        a0a = *(const float4*)(Ap0 + kf); a0b = *(const float4*)(Ap0 + kf + 4);
        a1a = *(const float4*)(Ap1 + kf); a1b = *(const float4*)(Ap1 + kf + 4);
      }
    }
    bf16x8 a[4], b[4];
    #pragma unroll
    for (int mi = 0; mi < 4; mi++) a[mi] = *(const bf16x8*)&AlP[cur][wr*64 + mi*16 + lr][g*8];
    #pragma unroll
    for (int ni = 0; ni < 4; ni++) b[ni] = *(const bf16x8*)&BlL[cur][(size_t)(wc*64 + ni*16 + lr) * 32 + g*8];
    #pragma unroll
    for (int mi = 0; mi < 4; mi++)
      #pragma unroll
      for (int ni = 0; ni < 4; ni++)
        acc[mi][ni] = mfma16(a[mi], b[ni], acc[mi][ni]);
    __syncthreads();
  }
  #pragma unroll
  for (int mi = 0; mi < 4; mi++)
    #pragma unroll
    for (int ni = 0; ni < 4; ni++) {
      int row0 = m0 + wr*64 + mi*16 + g*4;
      int col = n0 + wc*64 + ni*16 + lr;
      int bb = row0 >> 10, tt0 = row0 & 1023;
      int hh = col >> 6, dd = col & 63;
      if (hh < 16) {
        u16* p = dst0 + (((size_t)(bb*16 + hh) << 10) + (size_t)tt0) * 64 + dd;
        #pragma unroll
        for (int r = 0; r < 4; r++) p[(size_t)r * 64] = f2bf(acc[mi][ni][r] * scale);
      } else {
        union { u16 s[4]; uint2 u; } o;
        #pragma unroll
        for (int r = 0; r < 4; r++) o.s[r] = f2bf(acc[mi][ni][r]);
        *(uint2*)(Vb + (((size_t)((bb*16 + (hh - 16)) * 64 + dd)) << 10) + tt0) = o.u;
      }
    }
}

// ---------------- O-projection GEMM: dbuf global_load_lds both operands ----------------
__global__ __launch_bounds__(256) void k_gemm_bt(const u16* __restrict__ A, const u16* __restrict__ Bt,
                                                 u16* __restrict__ dst0, const float* __restrict__ bias) {
  __shared__ __align__(16) u16 AlL[2][128 * 32];
  __shared__ __align__(16) u16 BlL[2][128 * 32];
  int m0 = blockIdx.y * 128, n0 = blockIdx.x * 128;
  int tid = threadIdx.x;
  int w = tid >> 6, lane = tid & 63, g = lane >> 4, lr = lane & 15;
  int wr = w >> 1, wc = w & 1;
  f32x4 acc[4][4] = {};
  int srow = lane >> 2, scol = (lane & 3) * 8;
  const u16* Ag0 = &A[(size_t)(m0 + w * 16 + srow) * Dn + scol];
  const u16* Ag1 = &A[(size_t)(m0 + (w + 4) * 16 + srow) * Dn + scol];
  const u16* Bg0 = &Bt[(size_t)(n0 + w * 16 + srow) * Dn + scol];
  const u16* Bg1 = &Bt[(size_t)(n0 + (w + 4) * 16 + srow) * Dn + scol];

  // prologue: stage tile 0
  gload16(Ag0, &AlL[0][(size_t)w * 512]);
  gload16(Ag1, &AlL[0][(size_t)(w + 4) * 512]);
  gload16(Bg0, &BlL[0][(size_t)w * 512]);
  gload16(Bg1, &BlL[0][(size_t)(w + 4) * 512]);
  __syncthreads();

  for (int t = 0; t < 32; t++) {
    int cur = t & 1;
    if (t + 1 < 32) {
      int kn = (t + 1) * 32;
      gload16(Ag0 + kn, &AlL[cur ^ 1][(size_t)w * 512]);
      gload16(Ag1 + kn, &AlL[cur ^ 1][(size_t)(w + 4) * 512]);
      gload16(Bg0 + kn, &BlL[cur ^ 1][(size_t)w * 512]);
      gload16(Bg1 + kn, &BlL[cur ^ 1][(size_t)(w + 4) * 512]);
    }
    bf16x8 a[4], b[4];
    #pragma unroll
    for (int mi = 0; mi < 4; mi++) a[mi] = *(const bf16x8*)&AlL[cur][(size_t)(wr*64 + mi*16 + lr) * 32 + g*8];
    #pragma unroll
    for (int ni = 0; ni < 4; ni++) b[ni] = *(const bf16x8*)&BlL[cur][(size_t)(wc*64 + ni*16 + lr) * 32 + g*8];
    #pragma unroll
    for (int mi = 0; mi < 4; mi++)
      #pragma unroll
      for (int ni = 0; ni < 4; ni++)
        acc[mi][ni] = mfma16(a[mi], b[ni], acc[mi][ni]);
    __syncthreads();
  }
  #pragma unroll
  for (int mi = 0; mi < 4; mi++)
    #pragma unroll
    for (int ni = 0; ni < 4; ni++) {
      int row0 = m0 + wr*64 + mi*16 + g*4;
      int col = n0 + wc*64 + ni*16 + lr;
      #pragma unroll
      for (int r = 0; r < 4; r++)
        dst0[(size_t)(row0 + r) * Dn + col] = f2bf(acc[mi][ni][r] + bias[col]);
    }
}

// ---------------- flash attention with Music-Transformer skew ----------------
// (unchanged from round 9 — QBLK=32, shared K/V fragments, fixed-max softmax,
//  ones-MFMA row-sum, XOR-swizzled K, r6 load-order discipline)
__global__ __launch_bounds__(512, 2) void k_attn(const u16* __restrict__ Qb, const u16* __restrict__ Kb,
                                              const u16* __restrict__ VT, const u16* __restrict__ Eb,
                                              const unsigned long long* __restrict__ mbits,
                                              u16* __restrict__ ctx) {
  __shared__ __align__(16) u16 KlF[128 * 64];
  __shared__ __align__(16) u16 Vt[64][136];
  __shared__ __align__(16) u16 RP[8][16][72];
  int h = blockIdx.y;
  int b = blockIdx.x;
  int q0 = blockIdx.z * 256;
  int tid = threadIdx.x;
  int w = tid >> 6, lane = tid & 63, g = lane >> 4, lr = lane & 15;
  int qw0 = q0 + w * 32;
  size_t headoff = (size_t)(b * Hn + h) * Tn * DHn;
  bf16x8 qf0 = *(const bf16x8*)&Qb[headoff + (size_t)(qw0 + lr)*64 + g*8];
  bf16x8 qf1 = *(const bf16x8*)&Qb[headoff + (size_t)(qw0 + lr)*64 + 32 + g*8];
  bf16x8 qf2 = *(const bf16x8*)&Qb[headoff + (size_t)(qw0 + 16 + lr)*64 + g*8];
  bf16x8 qf3 = *(const bf16x8*)&Qb[headoff + (size_t)(qw0 + 16 + lr)*64 + 32 + g*8];
  f32x4 O[8] = {};
  f32x4 Os0 = {0.f, 0.f, 0.f, 0.f}, Os1 = {0.f, 0.f, 0.f, 0.f};
  union { u16 s[8]; bf16x8 v; } one8;
  #pragma unroll
  for (int j = 0; j < 8; j++) one8.s[j] = 0x3F80u;

  int srcl[4]; bool psel[4];
  #pragma unroll
  for (int r = 0; r < 4; r++) {
    int rowq = g*4 + r;
    srcl[r] = (lane & 48) + ((lr - rowq + 15) & 15);
    psel[r] = (lr <= rowq);
  }
  const unsigned long long* mrow = mbits + ((size_t)(b * Tn + qw0 + g*4) << 4);

  f32x4 carry0 = {0.f, 0.f, 0.f, 0.f}, carry1 = {0.f, 0.f, 0.f, 0.f};
  {
    int rm = 1008 - qw0;
    const u16* ep = &Eb[(size_t)(rm + lr) * 64 + g*8];
    carry0 = mfma16(qf0, *(const bf16x8*)ep, carry0);
    carry0 = mfma16(qf1, *(const bf16x8*)(ep + 32), carry0);
    const u16* ep1 = &Eb[(size_t)(rm - 16 + lr) * 64 + g*8];
    carry1 = mfma16(qf2, *(const bf16x8*)ep1, carry1);
    carry1 = mfma16(qf3, *(const bf16x8*)(ep1 + 32), carry1);
  }

  int sKr = tid >> 3, sKc = (tid & 7) * 8;
  int kswz = sKc ^ ((sKr & 7) << 3);
  int sVr = tid >> 4, sVc = (tid & 15) * 8;
  const u16* Kgs = Kb + headoff + (size_t)sKr * 64 + sKc;
  const u16* Vgs = VT + headoff + (size_t)sVr * 1024 + sVc;
  int4 kA = *(const int4*)Kgs;
  int4 kB = *(const int4*)(Kgs + (size_t)64 * 64);
  int4 vA = *(const int4*)Vgs;
  int4 vB = *(const int4*)(Vgs + 32 * 1024);

  int kread = (g * 8) ^ ((lr & 7) << 3);
  int kread2 = (32 + g * 8) ^ ((lr & 7) << 3);

  for (int k0 = 0; k0 < Tn; k0 += 128) {
    __syncthreads();
    *(int4*)&KlF[sKr * 64 + kswz]        = kA;
    *(int4*)&KlF[(sKr + 64) * 64 + kswz] = kB;
    *(int4*)&Vt[sVr][sVc]                = vA;
    *(int4*)&Vt[sVr + 32][sVc]           = vB;
    __syncthreads();

    uint2 mw0[2][4], mw1[2][4];
    #pragma unroll
    for (int t = 0; t < 2; t++)
      #pragma unroll
      for (int r = 0; r < 4; r++) {
        mw0[t][r] = *(const uint2*)(mrow + (size_t)r * 16 + (k0 >> 6) + t);
        mw1[t][r] = *(const uint2*)(mrow + 256 + (size_t)r * 16 + (k0 >> 6) + t);
      }

    int rmin0 = k0 - qw0 + 1008;
    bf16x8 pa000, pa001, pa010, pa011;
    bf16x8 pa100, pa101, pa110, pa111;

    bf16x8 e0[5][2];
    #pragma unroll
    for (int j = 0; j < 5; j++) {
      const u16* ep = &Eb[(size_t)(rmin0 + j*16 + lr) * 64 + g*8];
      e0[j][0] = *(const bf16x8*)ep;
      e0[j][1] = *(const bf16x8*)(ep + 32);
    }
    f32x4 Rm0[5], Rn0[5];
    Rm0[0] = carry0;
    Rn0[0] = carry1;
    __builtin_amdgcn_s_setprio(1);
    #pragma unroll
    for (int j = 1; j < 5; j++) {
      f32x4 R = {0.f, 0.f, 0.f, 0.f};
      R = mfma16(qf0, e0[j][0], R);
      R = mfma16(qf1, e0[j][1], R);
      Rm0[j] = R;
      f32x4 R2 = {0.f, 0.f, 0.f, 0.f};
      R2 = mfma16(qf2, e0[j-1][0], R2);
      R2 = mfma16(qf3, e0[j-1][1], R2);
      Rn0[j] = R2;
    }
    f32x4 S0[4], T0[4];
    #pragma unroll
    for (int c = 0; c < 4; c++) {
      int krow = c*16 + lr;
      bf16x8 kf0 = *(const bf16x8*)&KlF[krow*64 + kread];
      bf16x8 kf1 = *(const bf16x8*)&KlF[krow*64 + kread2];
      f32x4 z = {0.f, 0.f, 0.f, 0.f};
      z = mfma16(qf0, kf0, z); z = mfma16(qf1, kf1, z);
      S0[c] = z;
      f32x4 z2 = {0.f, 0.f, 0.f, 0.f};
      z2 = mfma16(qf2, kf0, z2); z2 = mfma16(qf3, kf1, z2);
      T0[c] = z2;
    }
    __builtin_amdgcn_s_setprio(0);
    {
      float sh[5][4], si[5][4];
      #pragma unroll
      for (int s5 = 0; s5 < 5; s5++)
        #pragma unroll
        for (int r = 0; r < 4; r++) {
          sh[s5][r] = __shfl(Rm0[s5][r], srcl[r], 64);
          si[s5][r] = __shfl(Rn0[s5][r], srcl[r], 64);
        }
      #pragma unroll
      for (int c = 0; c < 4; c++)
        #pragma unroll
        for (int r = 0; r < 4; r++) {
          float s = S0[c][r] + (psel[r] ? sh[c][r] : sh[c+1][r]);
          unsigned bit;
          if (c == 0)      bit = (mw0[0][r].x >> lr) & 1u;
          else if (c == 1) bit = (mw0[0][r].x >> (16 + lr)) & 1u;
          else if (c == 2) bit = (mw0[0][r].y >> lr) & 1u;
          else             bit = (mw0[0][r].y >> (16 + lr)) & 1u;
          s = bit ? -1e9f : s;
          RP[w][g*4 + r][c*16 + lr] = f2bf(__builtin_amdgcn_exp2f(s));
        }
      pa000 = *(const bf16x8*)&RP[w][lr][g*8];
      pa001 = *(const bf16x8*)&RP[w][lr][32 + g*8];
      #pragma unroll
      for (int c = 0; c < 4; c++)
        #pragma unroll
        for (int r = 0; r < 4; r++) {
          float s = T0[c][r] + (psel[r] ? si[c][r] : si[c+1][r]);
          unsigned bit;
          if (c == 0)      bit = (mw1[0][r].x >> lr) & 1u;
          else if (c == 1) bit = (mw1[0][r].x >> (16 + lr)) & 1u;
          else if (c == 2) bit = (mw1[0][r].y >> lr) & 1u;
          else             bit = (mw1[0][r].y >> (16 + lr)) & 1u;
          s = bit ? -1e9f : s;
          RP[w][g*4 + r][c*16 + lr] = f2bf(__builtin_amdgcn_exp2f(s));
        }
      pa010 = *(const bf16x8*)&RP[w][lr][g*8];
      pa011 = *(const bf16x8*)&RP[w][lr][32 + g*8];
    }

    bf16x8 e1[5][2];
    #pragma unroll
    for (int j = 0; j < 5; j++) {
      const u16* ep = &Eb[(size_t)(rmin0 + 64 + j*16 + lr) * 64 + g*8];
      e1[j][0] = *(const bf16x8*)ep;
      e1[j][1] = *(const bf16x8*)(ep + 32);
    }
    f32x4 Rm1[5], Rn1[5];
    Rm1[0] = Rm0[4];
    Rn1[0] = Rn0[4];
    __builtin_amdgcn_s_setprio(1);
    #pragma unroll
    for (int j = 1; j < 5; j++) {
      f32x4 R = {0.f, 0.f, 0.f, 0.f};
      R = mfma16(qf0, e1[j][0], R);
      R = mfma16(qf1, e1[j][1], R);
      Rm1[j] = R;
      f32x4 R2 = {0.f, 0.f, 0.f, 0.f};
      R2 = mfma16(qf2, e1[j-1][0], R2);
      R2 = mfma16(qf3, e1[j-1][1], R2);
      Rn1[j] = R2;
    }
    __builtin_amdgcn_s_setprio(0);
    carry0 = Rm1[4];
    carry1 = Rn1[4];

    __builtin_amdgcn_sched_barrier(0);
    if (k0 + 128 < Tn) {
      kA = *(const int4*)(Kgs + (size_t)(k0 + 128) * 64);
      kB = *(const int4*)(Kgs + (size_t)(k0 + 192) * 64);
      vA = *(const int4*)(Vgs + k0 + 128);
      vB = *(const int4*)(Vgs + 32 * 1024 + k0 + 128);
    }
    __builtin_amdgcn_sched_barrier(0);

    f32x4 S1[4], T1[4];
    __builtin_amdgcn_s_setprio(1);
    #pragma unroll
    for (int c = 0; c < 4; c++) {
      int krow = 64 + c*16 + lr;
      bf16x8 kf0 = *(const bf16x8*)&KlF[krow*64 + kread];
      bf16x8 kf1 = *(const bf16x8*)&KlF[krow*64 + kread2];
      f32x4 z = {0.f, 0.f, 0.f, 0.f};
      z = mfma16(qf0, kf0, z); z = mfma16(qf1, kf1, z);
      S1[c] = z;
      f32x4 z2 = {0.f, 0.f, 0.f, 0.f};
      z2 = mfma16(qf2, kf0, z2); z2 = mfma16(qf3, kf1, z2);
      T1[c] = z2;
    }
    __builtin_amdgcn_s_setprio(0);
    {
      float sh[5][4], si[5][4];
      #pragma unroll
      for (int s5 = 0; s5 < 5; s5++)
        #pragma unroll
        for (int r = 0; r < 4; r++) {
          sh[s5][r] = __shfl(Rm1[s5][r], srcl[r], 64);
          si[s5][r] = __shfl(Rn1[s5][r], srcl[r], 64);
        }
      #pragma unroll
      for (int c = 0; c < 4; c++)
        #pragma unroll
        for (int r = 0; r < 4; r++) {
          float s = S1[c][r] + (psel[r] ? sh[c][r] : sh[c+1][r]);
          unsigned bit;
          if (c == 0)      bit = (mw0[1][r].x >> lr) & 1u;
          else if (c == 1) bit = (mw0[1][r].x >> (16 + lr)) & 1u;
          else if (c == 2) bit = (mw0[1][r].y >> lr) & 1u;
          else             bit = (mw0[1][r].y >> (16 + lr)) & 1u;
          s = bit ? -1e9f : s;
          RP[w][g*4 + r][c*16 + lr] = f2bf(__builtin_amdgcn_exp2f(s));
        }
      pa100 = *(const bf16x8*)&RP[w][lr][g*8];
      pa101 = *(const bf16x8*)&RP[w][lr][32 + g*8];
      #pragma unroll
      for (int c = 0; c < 4; c++)
        #pragma unroll
        for (int r = 0; r < 4; r++) {
          float s = T1[c][r] + (psel[r] ? si[c][r] : si[c+1][r]);
          unsigned bit;
          if (c == 0)      bit = (mw1[1][r].x >> lr) & 1u;
          else if (c == 1) bit = (mw1[1][r].x >> (16 + lr)) & 1u;
          else if (c == 2) bit = (mw1[1][r].y >> lr) & 1u;
          else             bit = (mw1[1][r].y >> (16 + lr)) & 1u;
          s = bit ? -1e9f : s;
          RP[w][g*4 + r][c*16 + lr] = f2bf(__builtin_amdgcn_exp2f(s));
        }
      pa110 = *(const bf16x8*)&RP[w][lr][g*8];
      pa111 = *(const bf16x8*)&RP[w][lr][32 + g*8];
    }

    __builtin_amdgcn_s_setprio(1);
    #pragma unroll
    for (int ct = 0; ct < 4; ct++) {
      bf16x8 vf0 = *(const bf16x8*)&Vt[ct*16 + lr][g*8];
      bf16x8 vf1 = *(const bf16x8*)&Vt[ct*16 + lr][32 + g*8];
      bf16x8 vf2 = *(const bf16x8*)&Vt[ct*16 + lr][64 + g*8];
      bf16x8 vf3 = *(const bf16x8*)&Vt[ct*16 + lr][96 + g*8];
      O[ct] = mfma16(pa000, vf0, O[ct]);
      O[ct] = mfma16(pa001, vf1, O[ct]);
      O[ct] = mfma16(pa100, vf2, O[ct]);
      O[ct] = mfma16(pa101, vf3, O[ct]);
      O[4+ct] = mfma16(pa010, vf0, O[4+ct]);
      O[4+ct] = mfma16(pa011, vf1, O[4+ct]);
      O[4+ct] = mfma16(pa110, vf2, O[4+ct]);
      O[4+ct] = mfma16(pa111, vf3, O[4+ct]);
    }
    Os0 = mfma16(pa000, one8.v, Os0);
    Os0 = mfma16(pa001, one8.v, Os0);
    Os0 = mfma16(pa100, one8.v, Os0);
    Os0 = mfma16(pa101, one8.v, Os0);
    Os1 = mfma16(pa010, one8.v, Os1);
    Os1 = mfma16(pa011, one8.v, Os1);
    Os1 = mfma16(pa110, one8.v, Os1);
    Os1 = mfma16(pa111, one8.v, Os1);
    __builtin_amdgcn_s_setprio(0);
  }
  float inv0[4], inv1[4];
  #pragma unroll
  for (int r = 0; r < 4; r++) { inv0[r] = 1.f / Os0[r]; inv1[r] = 1.f / Os1[r]; }
  #pragma unroll
  for (int ct = 0; ct < 4; ct++)
    #pragma unroll
    for (int r = 0; r < 4; r++) {
      int rowq = g*4 + r, col = ct*16 + lr;
      ctx[(size_t)(b*Tn + qw0 + rowq) * 1024 + h*64 + col] = f2bf(O[ct][r] * inv0[r]);
      ctx[(size_t)(b*Tn + qw0 + 16 + rowq) * 1024 + h*64 + col] = f2bf(O[4+ct][r] * inv1[r]);
    }
}

// ---------------- residual + LayerNorm ----------------
__global__ __launch_bounds__(256) void k_ln(const float* __restrict__ x, const u16* __restrict__ o,
                                            const float* __restrict__ gamma, const float* __restrict__ beta,
                                            float* __restrict__ out) {
  int m = blockIdx.x, tid = threadIdx.x;
  int w = tid >> 6, lane = tid & 63;
  const float* xr = x + (size_t)m * Dn;
  const u16* orow = o + (size_t)m * Dn;
  float4 xv = *(const float4*)&xr[tid*4];
  union { uint2 u; u16 s[4]; } ou;
  ou.u = *(const uint2*)&orow[tid*4];
  float y[4];
  y[0] = xv.x + bf2f(ou.s[0]);
  y[1] = xv.y + bf2f(ou.s[1]);
  y[2] = xv.z + bf2f(ou.s[2]);
  y[3] = xv.w + bf2f(ou.s[3]);
  float s = y[0]+y[1]+y[2]+y[3];
  float s2 = y[0]*y[0]+y[1]*y[1]+y[2]*y[2]+y[3]*y[3];
  #pragma unroll
  for (int off = 1; off < 64; off <<= 1) { s += __shfl_xor(s, off); s2 += __shfl_xor(s2, off); }
  __shared__ float red[8];
  if (lane == 0) { red[w] = s; red[4 + w] = s2; }
  __syncthreads();
  float Sa = red[0]+red[1]+red[2]+red[3];
  float Sb = red[4]+red[5]+red[6]+red[7];
  float mu = Sa * (1.f/1024.f);
  float var = Sb * (1.f/1024.f) - mu*mu;
  float rstd = rsqrtf(var + 1e-5f);
  #pragma unroll
  for (int i = 0; i < 4; i++) {
    int j = tid*4 + i;
    out[(size_t)m*Dn + j] = (y[i] - mu) * rstd * gamma[j] + beta[j];
  }
}

extern "C" void kernel_launch(void* const* d_in, const int* in_sizes, int n_in,
                              void* d_out, int out_size, void* d_ws, size_t ws_size,
                              hipStream_t stream) {
  const float* x    = (const float*)d_in[0];
  const float* ctxI = (const float*)d_in[1];
  const unsigned char* mask = (const unsigned char*)d_in[2];
  const float* lut  = (const float*)d_in[3];
  const float* Wq   = (const float*)d_in[4];
  const float* Wk   = (const float*)d_in[5];
  const float* Wv   = (const float*)d_in[6];
  const float* Wo   = (const float*)d_in[7];
  const float* bo   = (const float*)d_in[8];
  const float* gamma= (const float*)d_in[9];
  const float* beta = (const float*)d_in[10];
  float* out = (float*)d_out;

  u16* WqT  = (u16*)d_ws;
  u16* WkT  = WqT + 1048576;
  u16* WvT  = WkT + 1048576;   // contiguous with WkT -> fused KV GEMM reads [2048][1024]
  u16* WoT  = WvT + 1048576;
  u16* Ebf  = WoT + 1048576;
  u16* Qbf  = Ebf + 131072;
  u16* Kbf  = Qbf + 4194304;
  u16* Vbf  = Kbf + 4194304;   // holds V^T [B,H,DH,T]
  u16* ctxb = Vbf + 4194304;
  u16* obf  = ctxb + 4194304;
  unsigned long long* mbits = (unsigned long long*)(obf + 4194304); // 65536 words = 512 KB

  k_maskpack<<<16384, 256, 0, stream>>>(mask, mbits);
  k_convert<<<128, 256, 0, stream>>>(lut, Ebf, 131008);
  dim3 tb(32, 8), tg4(32, 32, 4);
  k_transpose_convert4<<<tg4, tb, 0, stream>>>(Wq, Wk, Wv, Wo, WqT, WkT, WvT, WoT);
  k_proj<<<768, 256, 0, stream>>>(x, ctxI, WqT, WkT, Qbf, Kbf, Vbf);
  k_attn<<<dim3(4, 16, 4), 512, 0, stream>>>(Qbf, Kbf, Vbf, Ebf, mbits, ctxb);
  k_gemm_bt<<<dim3(8, 32), 256, 0, stream>>>(ctxb, WoT, obf, bo);
  k_ln<<<4096, 256, 0, stream>>>(x, obf, gamma, beta, out);
}